// Round 1
// baseline (838.069 us; speedup 1.0000x reference)
//
#include <hip/hip_runtime.h>
#include <math.h>

// ---------------------------------------------------------------------------
// Quantized CNN forward (PaddingNet). All convs run as exact int8 integer
// convolutions (sdot4) with float quant epilogues matching the reference's
// fake-quant chain (rintf == round-half-even == jnp.round).
// ---------------------------------------------------------------------------

#if defined(__has_builtin)
#  if __has_builtin(__builtin_amdgcn_sdot4)
#    define HAVE_SDOT4 1
#  endif
#endif

__device__ __forceinline__ int dot4(int a, int b, int c) {
#ifdef HAVE_SDOT4
  return __builtin_amdgcn_sdot4(a, b, c, false);
#else
  c += (int)(signed char)(a)       * (int)(signed char)(b);
  c += (int)(signed char)(a >> 8)  * (int)(signed char)(b >> 8);
  c += (int)(signed char)(a >> 16) * (int)(signed char)(b >> 16);
  c += (int)(signed char)(a >> 24) * (int)(signed char)(b >> 24);
  return c;
#endif
}

__device__ __forceinline__ int quant_clip(float v) {
  float r = rintf(v);
  r = fminf(fmaxf(r, -128.0f), 127.0f);
  return (int)r;
}

__device__ __forceinline__ int pack4i8(int q0, int q1, int q2, int q3) {
  return (q0 & 255) | ((q1 & 255) << 8) | ((q2 & 255) << 16) | ((q3 & 255) << 24);
}

// relu -> fake_quant(sA) -> fake_quant(sB); returns int8 code of the final quant
__device__ __forceinline__ int fq_chain(float y, float sA, float sB) {
  float v  = fmaxf(y, 0.0f);
  float r1 = fminf(rintf(v / sA), 127.0f);      // v>=0 so lower clip not needed
  float rv = r1 * sA;
  float r2 = fminf(fmaxf(rintf(rv / sB), -128.0f), 127.0f);
  return (int)r2;
}

// ---------------------------------------------------------------------------
// Weight quantization: one block per tensor. Packs input-channel groups of 4
// into int32 words laid out [O][KY][KX][I/4] for sdot4 consumption.
// ---------------------------------------------------------------------------
__global__ __launch_bounds__(256) void k_quant_weights(
    const float* __restrict__ w1, const float* __restrict__ w2,
    const float* __restrict__ w3, const float* __restrict__ w4,
    const float* __restrict__ wc, float* __restrict__ wscale,
    int* __restrict__ qw1, int* __restrict__ qw2, int* __restrict__ qw3,
    int* __restrict__ qw4, int* __restrict__ qwc)
{
  __shared__ float red[256];
  __shared__ float ssh;
  const int t = blockIdx.x, tid = threadIdx.x;
  const float* src = (t == 0) ? w1 : (t == 1) ? w2 : (t == 2) ? w3 : (t == 3) ? w4 : wc;
  const int nsrc   = (t == 0) ? 144 : (t == 1) ? 4608 : (t == 2) ? 25600 : (t == 3) ? 4608 : 160;

  float m = 0.0f;
  for (int i = tid; i < nsrc; i += 256) m = fmaxf(m, fabsf(src[i]));
  red[tid] = m;
  __syncthreads();
  for (int s = 128; s > 0; s >>= 1) {
    if (tid < s) red[tid] = fmaxf(red[tid], red[tid + s]);
    __syncthreads();
  }
  if (tid == 0) { ssh = red[0] / 127.0f; wscale[t] = ssh; }
  __syncthreads();
  const float s = ssh;

  if (t == 0) {                 // w1: [16][1][3][3] -> int per element [16][9]
    for (int i = tid; i < 144; i += 256) qw1[i] = quant_clip(w1[i] / s);
  } else if (t == 1) {          // w2: [32][16][3][3] -> [32][3][3][4] words
    for (int wi = tid; wi < 1152; wi += 256) {
      int o = wi / 36, r = wi % 36, ky = r / 12, r2 = r % 12, kx = r2 / 4, i4 = r2 % 4;
      int q[4];
      #pragma unroll
      for (int j = 0; j < 4; j++) {
        int sidx = ((o * 16 + i4 * 4 + j) * 3 + ky) * 3 + kx;
        q[j] = quant_clip(w2[sidx] / s);
      }
      qw2[wi] = pack4i8(q[0], q[1], q[2], q[3]);
    }
  } else if (t == 2) {          // w3: [32][32][5][5] -> [32][5][5][8] words
    for (int wi = tid; wi < 6400; wi += 256) {
      int o = wi / 200, r = wi % 200, ky = r / 40, r2 = r % 40, kx = r2 / 8, i4 = r2 % 8;
      int q[4];
      #pragma unroll
      for (int j = 0; j < 4; j++) {
        int sidx = ((o * 32 + i4 * 4 + j) * 5 + ky) * 5 + kx;
        q[j] = quant_clip(w3[sidx] / s);
      }
      qw3[wi] = pack4i8(q[0], q[1], q[2], q[3]);
    }
  } else if (t == 3) {          // w4: [16][32][3][3] -> [16][3][3][8] words
    for (int wi = tid; wi < 1152; wi += 256) {
      int o = wi / 72, r = wi % 72, ky = r / 24, r2 = r % 24, kx = r2 / 8, i4 = r2 % 8;
      int q[4];
      #pragma unroll
      for (int j = 0; j < 4; j++) {
        int sidx = ((o * 32 + i4 * 4 + j) * 3 + ky) * 3 + kx;
        q[j] = quant_clip(w4[sidx] / s);
      }
      qw4[wi] = pack4i8(q[0], q[1], q[2], q[3]);
    }
  } else {                      // wc: [10][16] -> [10][4] words
    for (int wi = tid; wi < 40; wi += 256) {
      int o = wi / 4, i4 = wi % 4;
      int q[4];
      #pragma unroll
      for (int j = 0; j < 4; j++) q[j] = quant_clip(wc[o * 16 + i4 * 4 + j] / s);
      qwc[wi] = pack4i8(q[0], q[1], q[2], q[3]);
    }
  }
}

// ---------------------------------------------------------------------------
// Input fake-quant: x[32*256*256] f32 -> int8 (packed words). 524288 words.
// ---------------------------------------------------------------------------
__global__ __launch_bounds__(256) void k_quant_input(
    const float* __restrict__ x, const float* __restrict__ scales,
    int* __restrict__ q0w)
{
  int i = blockIdx.x * 256 + threadIdx.x;
  if (i >= 524288) return;
  float s = scales[0];
  float4 v = ((const float4*)x)[i];
  q0w[i] = pack4i8(quant_clip(v.x / s), quant_clip(v.y / s),
                   quant_clip(v.z / s), quant_clip(v.w / s));
}

// ---------------------------------------------------------------------------
// conv1: 1->16ch, 3x3, pad0. In: q0 [32][256][256] i8. Out: a1 NHWC
// [32][254][254][16] i8 (4 words/pixel), fused relu1/quant1.
// ---------------------------------------------------------------------------
__global__ __launch_bounds__(256) void k_conv1(
    const signed char* __restrict__ q0, const int* __restrict__ qw1,
    const float* __restrict__ b1, const float* __restrict__ scales,
    const float* __restrict__ wscale, int* __restrict__ a1)
{
  __shared__ int wsh[144];
  if (threadIdx.x < 144) wsh[threadIdx.x] = qw1[threadIdx.x];
  __syncthreads();

  int pix = blockIdx.x * 256 + threadIdx.x;
  const int TOT = 32 * 254 * 254;
  if (pix >= TOT) return;
  int n = pix / (254 * 254), r = pix % (254 * 254);
  int oy = r / 254, ox = r % 254;

  int av[9];
  const signed char* base = q0 + (n * 256 + oy) * 256 + ox;
  #pragma unroll
  for (int ky = 0; ky < 3; ky++)
    #pragma unroll
    for (int kx = 0; kx < 3; kx++)
      av[ky * 3 + kx] = (int)base[ky * 256 + kx];

  float s1 = scales[1], s2 = scales[2];
  float scl = scales[0] * wscale[0];
  int outw[4];
  #pragma unroll
  for (int g = 0; g < 4; g++) {
    int q[4];
    #pragma unroll
    for (int j = 0; j < 4; j++) {
      int oc = g * 4 + j;
      int acc = 0;
      #pragma unroll
      for (int k = 0; k < 9; k++) acc += av[k] * wsh[oc * 9 + k];
      float y = fmaf(scl, (float)acc, b1[oc]);
      q[j] = fq_chain(y, s1, s2);
    }
    outw[g] = pack4i8(q[0], q[1], q[2], q[3]);
  }
  *(int4*)(a1 + pix * 4) = make_int4(outw[0], outw[1], outw[2], outw[3]);
}

// ---------------------------------------------------------------------------
// conv2: 16->32ch, 3x3, pad1. In: a1 NHWC i8 (4 words/px). Out: a2 NHWC
// [32][254][254][32] i8 (8 words/px), fused relu2/quant2. One thread = one
// pixel, all 32 oc; weights in LDS (wave-uniform broadcast reads).
// ---------------------------------------------------------------------------
__global__ __launch_bounds__(256) void k_conv2(
    const int* __restrict__ a1, const int* __restrict__ qw2,
    const float* __restrict__ b2, const float* __restrict__ scales,
    const float* __restrict__ wscale, int* __restrict__ a2)
{
  __shared__ int wsh[1152];
  for (int i = threadIdx.x; i < 1152; i += 256) wsh[i] = qw2[i];
  __syncthreads();

  int pix = blockIdx.x * 256 + threadIdx.x;
  const int TOT = 32 * 254 * 254;
  if (pix >= TOT) return;
  int n = pix / (254 * 254), r = pix % (254 * 254);
  int oy = r / 254, ox = r % 254;

  int acc[32];
  #pragma unroll
  for (int i = 0; i < 32; i++) acc[i] = 0;

  for (int ky = 0; ky < 3; ky++) {
    int iy = oy - 1 + ky;
    if (iy < 0 || iy >= 254) continue;
    for (int kx = 0; kx < 3; kx++) {
      int ix = ox - 1 + kx;
      if (ix < 0 || ix >= 254) continue;
      int4 av = *(const int4*)(a1 + ((n * 254 + iy) * 254 + ix) * 4);
      const int wb0 = ky * 12 + kx * 4;
      #pragma unroll
      for (int oc = 0; oc < 32; oc++) {
        int wb = oc * 36 + wb0;
        int s = acc[oc];
        s = dot4(av.x, wsh[wb + 0], s);
        s = dot4(av.y, wsh[wb + 1], s);
        s = dot4(av.z, wsh[wb + 2], s);
        s = dot4(av.w, wsh[wb + 3], s);
        acc[oc] = s;
      }
    }
  }

  float s3 = scales[3], s4 = scales[4];
  float scl = scales[2] * wscale[1];
  int outw[8];
  #pragma unroll
  for (int g = 0; g < 8; g++) {
    int q[4];
    #pragma unroll
    for (int j = 0; j < 4; j++) {
      int oc = g * 4 + j;
      float y = fmaf(scl, (float)acc[oc], b2[oc]);
      q[j] = fq_chain(y, s3, s4);
    }
    outw[g] = pack4i8(q[0], q[1], q[2], q[3]);
  }
  int4* dst = (int4*)(a2 + pix * 8);
  dst[0] = make_int4(outw[0], outw[1], outw[2], outw[3]);
  dst[1] = make_int4(outw[4], outw[5], outw[6], outw[7]);
}

// ---------------------------------------------------------------------------
// conv3 + quant3 + maxpool(2x2) + pool_quant fused.
// In: a2 NHWC [32][254][254][32] i8, pad2, 5x5, 32->32ch.
// Each thread: one pooled pixel (Y,X), 2x2 conv outputs, 8 oc (threadIdx.y
// picks the oc-group -> wave-uniform LDS weight reads).
// Out: a3p NHWC [32][127][127][32] i8 (8 words/px).
// ---------------------------------------------------------------------------
__global__ __launch_bounds__(256) void k_conv3pool(
    const int* __restrict__ a2, const int* __restrict__ qw3,
    const float* __restrict__ b3, const float* __restrict__ scales,
    const float* __restrict__ wscale, int* __restrict__ a3p)
{
  __shared__ int wsh[6400];
  {
    int tid = threadIdx.y * 64 + threadIdx.x;
    for (int i = tid; i < 6400; i += 256) wsh[i] = qw3[i];
  }
  __syncthreads();

  int p = blockIdx.x * 64 + threadIdx.x;
  const int TOT = 32 * 127 * 127;
  if (p >= TOT) return;
  int n = p / (127 * 127), r = p % (127 * 127);
  int Y = r / 127, X = r % 127;
  int y0 = 2 * Y, x0 = 2 * X;
  int ocg = threadIdx.y;

  int acc[4][8];
  #pragma unroll
  for (int i = 0; i < 4; i++)
    #pragma unroll
    for (int j = 0; j < 8; j++) acc[i][j] = 0;

  for (int ky = 0; ky < 5; ky++) {
    int iy = y0 - 2 + ky;
    for (int kx = 0; kx < 5; kx++) {
      int ix = x0 - 2 + kx;
      int a[2][2][8];
      #pragma unroll
      for (int dy = 0; dy < 2; dy++) {
        int yy = iy + dy;
        bool vy = (yy >= 0) && (yy < 254);
        #pragma unroll
        for (int dx = 0; dx < 2; dx++) {
          int xx = ix + dx;
          if (vy && xx >= 0 && xx < 254) {
            const int4* src = (const int4*)(a2 + ((n * 254 + yy) * 254 + xx) * 8);
            int4 lo = src[0], hi = src[1];
            a[dy][dx][0] = lo.x; a[dy][dx][1] = lo.y; a[dy][dx][2] = lo.z; a[dy][dx][3] = lo.w;
            a[dy][dx][4] = hi.x; a[dy][dx][5] = hi.y; a[dy][dx][6] = hi.z; a[dy][dx][7] = hi.w;
          } else {
            #pragma unroll
            for (int w = 0; w < 8; w++) a[dy][dx][w] = 0;
          }
        }
      }
      #pragma unroll
      for (int o = 0; o < 8; o++) {
        int wb = (ocg * 8 + o) * 200 + ky * 40 + kx * 8;
        #pragma unroll
        for (int dy = 0; dy < 2; dy++)
          #pragma unroll
          for (int dx = 0; dx < 2; dx++) {
            int s = acc[dy * 2 + dx][o];
            #pragma unroll
            for (int w = 0; w < 8; w++) s = dot4(a[dy][dx][w], wsh[wb + w], s);
            acc[dy * 2 + dx][o] = s;
          }
      }
    }
  }

  float s5 = scales[5], s6 = scales[6], s7 = scales[7];
  float scl = scales[4] * wscale[2];
  int q7[8];
  #pragma unroll
  for (int o = 0; o < 8; o++) {
    int oc = ocg * 8 + o;
    float bo = b3[oc];
    int m = -1000;
    #pragma unroll
    for (int pp = 0; pp < 4; pp++) {
      float y = fmaf(scl, (float)acc[pp][o], bo);
      int q6 = fq_chain(y, s5, s6);
      m = max(m, q6);
    }
    float pm = (float)m * s6;                       // pooled value
    float r3 = fminf(fmaxf(rintf(pm / s7), -128.0f), 127.0f);
    q7[o] = (int)r3;
  }
  int w0 = pack4i8(q7[0], q7[1], q7[2], q7[3]);
  int w1 = pack4i8(q7[4], q7[5], q7[6], q7[7]);
  *(int2*)(a3p + p * 8 + ocg * 2) = make_int2(w0, w1);
}

// ---------------------------------------------------------------------------
// conv4: 32->16ch, 3x3, pad0. In: a3p [32][127][127][32] i8. Out: a4
// [32][125][125][16] i8 (4 words/px), fused relu4/quant4.
// ---------------------------------------------------------------------------
__global__ __launch_bounds__(256) void k_conv4(
    const int* __restrict__ a3p, const int* __restrict__ qw4,
    const float* __restrict__ b4, const float* __restrict__ scales,
    const float* __restrict__ wscale, int* __restrict__ a4)
{
  __shared__ int wsh[1152];
  for (int i = threadIdx.x; i < 1152; i += 256) wsh[i] = qw4[i];
  __syncthreads();

  int pix = blockIdx.x * 256 + threadIdx.x;
  const int TOT = 32 * 125 * 125;
  if (pix >= TOT) return;
  int n = pix / (125 * 125), r = pix % (125 * 125);
  int oy = r / 125, ox = r % 125;

  int acc[16];
  #pragma unroll
  for (int i = 0; i < 16; i++) acc[i] = 0;

  for (int ky = 0; ky < 3; ky++) {
    int iy = oy + ky;
    for (int kx = 0; kx < 3; kx++) {
      int ix = ox + kx;
      const int4* src = (const int4*)(a3p + ((n * 127 + iy) * 127 + ix) * 8);
      int4 lo = src[0], hi = src[1];
      int av[8] = {lo.x, lo.y, lo.z, lo.w, hi.x, hi.y, hi.z, hi.w};
      const int wb0 = ky * 24 + kx * 8;
      #pragma unroll
      for (int oc = 0; oc < 16; oc++) {
        int wb = oc * 72 + wb0;
        int s = acc[oc];
        #pragma unroll
        for (int w = 0; w < 8; w++) s = dot4(av[w], wsh[wb + w], s);
        acc[oc] = s;
      }
    }
  }

  float s8 = scales[8], s9 = scales[9];
  float scl = scales[7] * wscale[3];
  int outw[4];
  #pragma unroll
  for (int g = 0; g < 4; g++) {
    int q[4];
    #pragma unroll
    for (int j = 0; j < 4; j++) {
      int oc = g * 4 + j;
      float y = fmaf(scl, (float)acc[oc], b4[oc]);
      q[j] = fq_chain(y, s8, s9);
    }
    outw[g] = pack4i8(q[0], q[1], q[2], q[3]);
  }
  *(int4*)(a4 + pix * 4) = make_int4(outw[0], outw[1], outw[2], outw[3]);
}

// ---------------------------------------------------------------------------
// Global avg pool + pool_quant + classifier. One block per batch image.
// ---------------------------------------------------------------------------
__global__ __launch_bounds__(256) void k_gap_fc(
    const int* __restrict__ a4, const int* __restrict__ qwc,
    const float* __restrict__ bc, const float* __restrict__ scales,
    const float* __restrict__ wscale, float* __restrict__ out)
{
  __shared__ int sh[256][16];
  __shared__ int sq[16];
  int n = blockIdx.x, tid = threadIdx.x;

  int loc[16];
  #pragma unroll
  for (int i = 0; i < 16; i++) loc[i] = 0;
  for (int p = tid; p < 15625; p += 256) {
    int4 v = *(const int4*)(a4 + (n * 15625 + p) * 4);
    int w[4] = {v.x, v.y, v.z, v.w};
    #pragma unroll
    for (int wi = 0; wi < 4; wi++)
      #pragma unroll
      for (int j = 0; j < 4; j++)
        loc[wi * 4 + j] += (int)(signed char)(w[wi] >> (8 * j));
  }
  #pragma unroll
  for (int i = 0; i < 16; i++) sh[tid][i] = loc[i];
  __syncthreads();

  if (tid < 16) {
    int s = 0;
    for (int t = 0; t < 256; t++) s += sh[t][tid];
    float v = scales[9] * (float)s / 15625.0f;                 // GAP mean
    float r = fminf(fmaxf(rintf(v / scales[10]), -128.0f), 127.0f);
    sq[tid] = (int)r;
  }
  __syncthreads();

  if (tid < 10) {
    int acc = 0;
    #pragma unroll
    for (int k4 = 0; k4 < 4; k4++) {
      int wv = qwc[tid * 4 + k4];
      #pragma unroll
      for (int j = 0; j < 4; j++)
        acc += sq[k4 * 4 + j] * (int)(signed char)(wv >> (8 * j));
    }
    out[n * 10 + tid] = fmaf(scales[10] * wscale[4], (float)acc, bc[tid]);
  }
}

// ---------------------------------------------------------------------------
// Launch. Workspace layout (bytes), peak ~96.6 MB:
//   0      wscale[8]          (5 used)
//   64     qw1   144 ints
//   1024   qw2   1152 ints
//   8192   qw3   6400 ints
//   36864  qw4   1152 ints
//   43008  qwc   40 ints
//   65536        a2 (66,064,384 B)   ... later reused as a4 (8,000,000 B)
//   66129920     a1 (33,032,192 B)   ... later reused as a3p (16,516,096 B)
//   99162112     q0 (2,097,152 B)
// ---------------------------------------------------------------------------
extern "C" void kernel_launch(void* const* d_in, const int* in_sizes, int n_in,
                              void* d_out, int out_size, void* d_ws, size_t ws_size,
                              hipStream_t stream) {
  const float* x  = (const float*)d_in[0];
  const float* w1 = (const float*)d_in[1];
  const float* b1 = (const float*)d_in[2];
  const float* w2 = (const float*)d_in[3];
  const float* b2 = (const float*)d_in[4];
  const float* w3 = (const float*)d_in[5];
  const float* b3 = (const float*)d_in[6];
  const float* w4 = (const float*)d_in[7];
  const float* b4 = (const float*)d_in[8];
  const float* wc = (const float*)d_in[9];
  const float* bc = (const float*)d_in[10];
  const float* sc = (const float*)d_in[11];

  char* ws = (char*)d_ws;
  float* wscale = (float*)(ws + 0);
  int* qw1 = (int*)(ws + 64);
  int* qw2 = (int*)(ws + 1024);
  int* qw3 = (int*)(ws + 8192);
  int* qw4 = (int*)(ws + 36864);
  int* qwc = (int*)(ws + 43008);
  int* a2  = (int*)(ws + 65536);
  int* a4  = (int*)(ws + 65536);        // reuses a2 region (a2 dead by conv4)
  int* a1  = (int*)(ws + 66129920);
  int* a3p = (int*)(ws + 66129920);     // reuses a1 region (a1 dead by conv3)
  int* q0  = (int*)(ws + 99162112);
  float* out = (float*)d_out;

  k_quant_weights<<<5, 256, 0, stream>>>(w1, w2, w3, w4, wc, wscale,
                                         qw1, qw2, qw3, qw4, qwc);
  k_quant_input<<<2048, 256, 0, stream>>>(x, sc, q0);
  k_conv1<<<8065, 256, 0, stream>>>((const signed char*)q0, qw1, b1, sc, wscale, a1);
  k_conv2<<<8065, 256, 0, stream>>>(a1, qw2, b2, sc, wscale, a2);
  k_conv3pool<<<8065, dim3(64, 4), 0, stream>>>(a2, qw3, b3, sc, wscale, a3p);
  k_conv4<<<1954, 256, 0, stream>>>(a3p, qw4, b4, sc, wscale, a4);
  k_gap_fc<<<32, 256, 0, stream>>>(a4, qwc, bc, sc, wscale, out);
}

// Round 4
// 420.428 us; speedup vs baseline: 1.9934x; 1.9934x over previous
//
#include <hip/hip_runtime.h>
#include <math.h>

// ---------------------------------------------------------------------------
// Quantized CNN forward (PaddingNet). conv2/conv3 run on the i8 MFMA pipe
// (v_mfma_i32_32x32x32_i8, implicit im2col); conv1/conv4 remain sdot4/IMAD.
// All integer math exact; float quant epilogues match the reference chain.
// ---------------------------------------------------------------------------

typedef int i32x4  __attribute__((ext_vector_type(4)));
typedef int i32x16 __attribute__((ext_vector_type(16)));

#if defined(__has_builtin)
#  if __has_builtin(__builtin_amdgcn_sdot4)
#    define HAVE_SDOT4 1
#  endif
#endif

__device__ __forceinline__ int dot4(int a, int b, int c) {
#ifdef HAVE_SDOT4
  return __builtin_amdgcn_sdot4(a, b, c, false);
#else
  c += (int)(signed char)(a)       * (int)(signed char)(b);
  c += (int)(signed char)(a >> 8)  * (int)(signed char)(b >> 8);
  c += (int)(signed char)(a >> 16) * (int)(signed char)(b >> 16);
  c += (int)(signed char)(a >> 24) * (int)(signed char)(b >> 24);
  return c;
#endif
}

__device__ __forceinline__ int quant_clip(float v) {
  float r = rintf(v);
  r = fminf(fmaxf(r, -128.0f), 127.0f);
  return (int)r;
}

__device__ __forceinline__ int pack4i8(int q0, int q1, int q2, int q3) {
  return (q0 & 255) | ((q1 & 255) << 8) | ((q2 & 255) << 16) | ((q3 & 255) << 24);
}

// relu -> fake_quant(sA) -> fake_quant(sB); returns int8 code of the final quant
__device__ __forceinline__ int fq_chain(float y, float sA, float sB) {
  float v  = fmaxf(y, 0.0f);
  float r1 = fminf(rintf(v / sA), 127.0f);
  float rv = r1 * sA;
  float r2 = fminf(fmaxf(rintf(rv / sB), -128.0f), 127.0f);
  return (int)r2;
}

// ---------------------------------------------------------------------------
// Weight quantization + MFMA B-fragment packing.
//  qw1: [16][9] ints (conv1 IMAD path)
//  qw2B: [6 ksteps][64 lanes][4 words]  (kstep = ky*2 + kxpair; k = 2 px * 16ic)
//  qw3B: [25 taps][64 lanes][4 words]   (k = 32 ic of one tap)
//  qw4: [16][3][3][8] words (sdot4)     qwc: [10][4] words
// B-fragment mapping: lane l -> col(oc)=l&31, k=(l>>5)*16 + word*4 + byte.
// ---------------------------------------------------------------------------
__global__ __launch_bounds__(256) void k_quant_weights(
    const float* __restrict__ w1, const float* __restrict__ w2,
    const float* __restrict__ w3, const float* __restrict__ w4,
    const float* __restrict__ wc, float* __restrict__ wscale,
    int* __restrict__ qw1, int* __restrict__ qw2B, int* __restrict__ qw3B,
    int* __restrict__ qw4, int* __restrict__ qwc)
{
  __shared__ float red[256];
  __shared__ float ssh;
  const int t = blockIdx.x, tid = threadIdx.x;
  const float* src = (t == 0) ? w1 : (t == 1) ? w2 : (t == 2) ? w3 : (t == 3) ? w4 : wc;
  const int nsrc   = (t == 0) ? 144 : (t == 1) ? 4608 : (t == 2) ? 25600 : (t == 3) ? 4608 : 160;

  float m = 0.0f;
  for (int i = tid; i < nsrc; i += 256) m = fmaxf(m, fabsf(src[i]));
  red[tid] = m;
  __syncthreads();
  for (int s = 128; s > 0; s >>= 1) {
    if (tid < s) red[tid] = fmaxf(red[tid], red[tid + s]);
    __syncthreads();
  }
  if (tid == 0) { ssh = red[0] / 127.0f; wscale[t] = ssh; }
  __syncthreads();
  const float s = ssh;

  if (t == 0) {                 // w1: [16][1][3][3] -> int per element [16][9]
    for (int i = tid; i < 144; i += 256) qw1[i] = quant_clip(w1[i] / s);
  } else if (t == 1) {          // w2 -> MFMA B fragments, 6 ksteps
    for (int wi = tid; wi < 1536; wi += 256) {
      int step = wi >> 8, rem = wi & 255;
      int ln = rem >> 2, w = rem & 3;
      int oc = ln & 31, h = ln >> 5;
      int ky = step >> 1, kxp = (step & 1) * 2;
      int q[4];
      #pragma unroll
      for (int j = 0; j < 4; j++) {
        int k = h * 16 + w * 4 + j;
        int ic = k & 15, kx = kxp + (k >> 4);
        float val = (kx < 3) ? w2[((oc * 16 + ic) * 3 + ky) * 3 + kx] : 0.0f;
        q[j] = quant_clip(val / s);
      }
      qw2B[wi] = pack4i8(q[0], q[1], q[2], q[3]);
    }
  } else if (t == 2) {          // w3 -> MFMA B fragments, 25 taps
    for (int wi = tid; wi < 6400; wi += 256) {
      int tap = wi >> 8, rem = wi & 255;
      int ln = rem >> 2, w = rem & 3;
      int oc = ln & 31, h = ln >> 5;
      int ky = tap / 5, kx = tap % 5;
      int q[4];
      #pragma unroll
      for (int j = 0; j < 4; j++) {
        int ic = h * 16 + w * 4 + j;
        q[j] = quant_clip(w3[((oc * 32 + ic) * 5 + ky) * 5 + kx] / s);
      }
      qw3B[wi] = pack4i8(q[0], q[1], q[2], q[3]);
    }
  } else if (t == 3) {          // w4: [16][32][3][3] -> [16][3][3][8] words
    for (int wi = tid; wi < 1152; wi += 256) {
      int o = wi / 72, r = wi % 72, ky = r / 24, r2 = r % 24, kx = r2 / 8, i4 = r2 % 8;
      int q[4];
      #pragma unroll
      for (int j = 0; j < 4; j++) {
        int sidx = ((o * 32 + i4 * 4 + j) * 3 + ky) * 3 + kx;
        q[j] = quant_clip(w4[sidx] / s);
      }
      qw4[wi] = pack4i8(q[0], q[1], q[2], q[3]);
    }
  } else {                      // wc: [10][16] -> [10][4] words
    for (int wi = tid; wi < 40; wi += 256) {
      int o = wi / 4, i4 = wi % 4;
      int q[4];
      #pragma unroll
      for (int j = 0; j < 4; j++) q[j] = quant_clip(wc[o * 16 + i4 * 4 + j] / s);
      qwc[wi] = pack4i8(q[0], q[1], q[2], q[3]);
    }
  }
}

// ---------------------------------------------------------------------------
// Input fake-quant: x[32*256*256] f32 -> int8 packed words.
// ---------------------------------------------------------------------------
__global__ __launch_bounds__(256) void k_quant_input(
    const float* __restrict__ x, const float* __restrict__ scales,
    int* __restrict__ q0w)
{
  int i = blockIdx.x * 256 + threadIdx.x;
  if (i >= 524288) return;
  float s = scales[0];
  float4 v = ((const float4*)x)[i];
  q0w[i] = pack4i8(quant_clip(v.x / s), quant_clip(v.y / s),
                   quant_clip(v.z / s), quant_clip(v.w / s));
}

// ---------------------------------------------------------------------------
// conv1: 1->16ch, 3x3, pad0 (IMAD). Out a1 NHWC [32][254][254][16].
// ---------------------------------------------------------------------------
__global__ __launch_bounds__(256) void k_conv1(
    const signed char* __restrict__ q0, const int* __restrict__ qw1,
    const float* __restrict__ b1, const float* __restrict__ scales,
    const float* __restrict__ wscale, int* __restrict__ a1)
{
  __shared__ int wsh[144];
  if (threadIdx.x < 144) wsh[threadIdx.x] = qw1[threadIdx.x];
  __syncthreads();

  int pix = blockIdx.x * 256 + threadIdx.x;
  const int TOT = 32 * 254 * 254;
  if (pix >= TOT) return;
  int n = pix / (254 * 254), r = pix % (254 * 254);
  int oy = r / 254, ox = r % 254;

  int av[9];
  const signed char* base = q0 + (n * 256 + oy) * 256 + ox;
  #pragma unroll
  for (int ky = 0; ky < 3; ky++)
    #pragma unroll
    for (int kx = 0; kx < 3; kx++)
      av[ky * 3 + kx] = (int)base[ky * 256 + kx];

  float s1 = scales[1], s2 = scales[2];
  float scl = scales[0] * wscale[0];
  int outw[4];
  #pragma unroll
  for (int g = 0; g < 4; g++) {
    int q[4];
    #pragma unroll
    for (int j = 0; j < 4; j++) {
      int oc = g * 4 + j;
      int acc = 0;
      #pragma unroll
      for (int k = 0; k < 9; k++) acc += av[k] * wsh[oc * 9 + k];
      float y = fmaf(scl, (float)acc, b1[oc]);
      q[j] = fq_chain(y, s1, s2);
    }
    outw[g] = pack4i8(q[0], q[1], q[2], q[3]);
  }
  *(int4*)(a1 + pix * 4) = make_int4(outw[0], outw[1], outw[2], outw[3]);
}

// ---------------------------------------------------------------------------
// conv2 via MFMA: 16->32ch, 3x3, pad1. M=32 pixels (1 row x 32 cols),
// N=32 oc, K=144 padded to 6 steps of 32 (2 adjacent pixels x 16 ic).
// Reads unpadded a1 (per-lane masked loads). Writes zero-padded a2p
// [32][258][258][32] i8 interior (border pre-zeroed by memset).
// ---------------------------------------------------------------------------
__global__ __launch_bounds__(256) void k_conv2_mfma(
    const int* __restrict__ a1, const int* __restrict__ qw2B,
    const float* __restrict__ b2, const float* __restrict__ scales,
    const float* __restrict__ wscale, signed char* __restrict__ a2p)
{
  const int lane = threadIdx.x & 63;
  const int bid = blockIdx.x;
  const int swz = (bid & 7) * 256 + (bid >> 3);     // XCD-chunked (2048 % 8 == 0)
  const int gw = swz * 4 + (threadIdx.x >> 6);

  i32x4 bw[6];
  #pragma unroll
  for (int t = 0; t < 6; t++)
    bw[t] = *(const i32x4*)(qw2B + (t * 64 + lane) * 4);

  const float s3 = scales[3], s4 = scales[4];
  const float scl = scales[2] * wscale[1];
  const int oc = lane & 31, h = lane >> 5, rr = lane & 31;
  const float bias = b2[oc];

  const int TILES = 32 * 254 * 8;
  #pragma unroll 1
  for (int t8 = 0; t8 < 8; t8++) {
    int tile = gw * 8 + t8;
    if (tile >= TILES) break;
    int n = tile / (254 * 8);
    int r = tile % (254 * 8);
    int y = r >> 3, X0 = (r & 7) * 32;

    i32x16 acc;
    #pragma unroll
    for (int z = 0; z < 16; z++) acc[z] = 0;

    #pragma unroll
    for (int ky = 0; ky < 3; ky++) {
      int iy = y + ky - 1;
      if (iy < 0 || iy >= 254) continue;            // wave-uniform
      #pragma unroll
      for (int kp = 0; kp < 2; kp++) {
        int ix = X0 + rr + kp * 2 + h - 1;
        i32x4 a;
        a[0] = 0; a[1] = 0; a[2] = 0; a[3] = 0;
        if (ix >= 0 && ix < 254)
          a = *(const i32x4*)(a1 + ((n * 254 + iy) * 254 + ix) * 4);
        acc = __builtin_amdgcn_mfma_i32_32x32x32_i8(a, bw[ky * 2 + kp], acc, 0, 0, 0);
      }
    }

    // C layout: col=lane&31, row=(reg&3)+8*(reg>>2)+4*(lane>>5)
    #pragma unroll
    for (int q = 0; q < 4; q++) {
      #pragma unroll
      for (int j = 0; j < 4; j++) {
        int row = j + 8 * q + 4 * h;
        int x = X0 + row;
        float yv = fmaf(scl, (float)acc[q * 4 + j], bias);
        int code = fq_chain(yv, s3, s4);
        if (x < 254)
          a2p[((size_t)(n * 258 + (y + 2)) * 258 + (x + 2)) * 32 + oc] = (signed char)code;
      }
    }
  }
}

// ---------------------------------------------------------------------------
// conv3 + quant3 + maxpool2x2 + pool_quant via MFMA.
// M=32 conv pixels = 8 pooled px x (dy,dx); m = pp*4 + dy*2 + dx so each
// pool window lands in one lane's reg-quad. N=32 oc, K=25 taps x 32ic.
// Reads padded a2p. Out a3p NHWC [32][127][127][32] i8.
// ---------------------------------------------------------------------------
__global__ __launch_bounds__(256) void k_conv3pool_mfma(
    const signed char* __restrict__ a2p, const int* __restrict__ qw3B,
    const float* __restrict__ b3, const float* __restrict__ scales,
    const float* __restrict__ wscale, signed char* __restrict__ a3p)
{
  const int lane = threadIdx.x & 63;
  const int bid = blockIdx.x;
  const int swz = (bid & 7) * 256 + (bid >> 3);
  const int gw = swz * 4 + (threadIdx.x >> 6);

  i32x4 bw[25];
  #pragma unroll
  for (int t = 0; t < 25; t++)
    bw[t] = *(const i32x4*)(qw3B + (t * 64 + lane) * 4);

  const float s5 = scales[5], s6 = scales[6], s7 = scales[7];
  const float scl = scales[4] * wscale[2];
  const int oc = lane & 31, h = lane >> 5;
  const float bias = b3[oc];

  const int rr = lane & 31;
  const int pp = rr >> 2, dy = (rr >> 1) & 1, dx = rr & 1;

  const int TILES = 32 * 127 * 16;
  #pragma unroll 1
  for (int t8 = 0; t8 < 8; t8++) {
    int tile = gw * 8 + t8;
    if (tile >= TILES) break;
    int n = tile / (127 * 16);
    int r = tile % (127 * 16);
    int Y = r >> 4, X0 = (r & 15) * 8;

    int py = 2 * Y + dy;                 // padded row base (tap ky adds)
    int px = 2 * (X0 + pp) + dx;         // padded col base (tap kx adds)
    px = min(px, 253);                   // clamp invalid (X>=127) lanes in-bounds
    const signed char* abase = a2p + ((size_t)(n * 258 + py) * 258 + px) * 32 + h * 16;

    i32x16 acc;
    #pragma unroll
    for (int z = 0; z < 16; z++) acc[z] = 0;

    #pragma unroll
    for (int ky = 0; ky < 5; ky++) {
      const signed char* rb = abase + ky * (258 * 32);
      #pragma unroll
      for (int kx = 0; kx < 5; kx++) {
        i32x4 a = *(const i32x4*)(rb + kx * 32);
        acc = __builtin_amdgcn_mfma_i32_32x32x32_i8(a, bw[ky * 5 + kx], acc, 0, 0, 0);
      }
    }

    // lane holds pooled blocks b = 2q + h as reg-quads q
    #pragma unroll
    for (int q = 0; q < 4; q++) {
      int b = 2 * q + h;
      int X = X0 + b;
      int m = -1000;
      #pragma unroll
      for (int j = 0; j < 4; j++) {
        float yv = fmaf(scl, (float)acc[q * 4 + j], bias);
        int q6 = fq_chain(yv, s5, s6);
        m = max(m, q6);
      }
      float pm = (float)m * s6;
      float r3 = fminf(fmaxf(rintf(pm / s7), -128.0f), 127.0f);
      if (X < 127)
        a3p[((size_t)(n * 127 + Y) * 127 + X) * 32 + oc] = (signed char)(int)r3;
    }
  }
}

// ---------------------------------------------------------------------------
// conv4: 32->16ch, 3x3, pad0 (sdot4). In a3p [32][127][127][32] i8.
// Out a4 [32][125][125][16] i8 words, fused relu4/quant4.
// ---------------------------------------------------------------------------
__global__ __launch_bounds__(256) void k_conv4(
    const int* __restrict__ a3p, const int* __restrict__ qw4,
    const float* __restrict__ b4, const float* __restrict__ scales,
    const float* __restrict__ wscale, int* __restrict__ a4)
{
  __shared__ int wsh[1152];
  for (int i = threadIdx.x; i < 1152; i += 256) wsh[i] = qw4[i];
  __syncthreads();

  int pix = blockIdx.x * 256 + threadIdx.x;
  const int TOT = 32 * 125 * 125;
  if (pix >= TOT) return;
  int n = pix / (125 * 125), r = pix % (125 * 125);
  int oy = r / 125, ox = r % 125;

  int acc[16];
  #pragma unroll
  for (int i = 0; i < 16; i++) acc[i] = 0;

  for (int ky = 0; ky < 3; ky++) {
    int iy = oy + ky;
    for (int kx = 0; kx < 3; kx++) {
      int ix = ox + kx;
      const int4* src = (const int4*)(a3p + ((n * 127 + iy) * 127 + ix) * 8);
      int4 lo = src[0], hi = src[1];
      int av[8] = {lo.x, lo.y, lo.z, lo.w, hi.x, hi.y, hi.z, hi.w};
      const int wb0 = ky * 24 + kx * 8;
      #pragma unroll
      for (int oc = 0; oc < 16; oc++) {
        int wb = oc * 72 + wb0;
        int s = acc[oc];
        #pragma unroll
        for (int w = 0; w < 8; w++) s = dot4(av[w], wsh[wb + w], s);
        acc[oc] = s;
      }
    }
  }

  float s8 = scales[8], s9 = scales[9];
  float scl = scales[7] * wscale[3];
  int outw[4];
  #pragma unroll
  for (int g = 0; g < 4; g++) {
    int q[4];
    #pragma unroll
    for (int j = 0; j < 4; j++) {
      int oc = g * 4 + j;
      float y = fmaf(scl, (float)acc[oc], b4[oc]);
      q[j] = fq_chain(y, s8, s9);
    }
    outw[g] = pack4i8(q[0], q[1], q[2], q[3]);
  }
  *(int4*)(a4 + pix * 4) = make_int4(outw[0], outw[1], outw[2], outw[3]);
}

// ---------------------------------------------------------------------------
// Global avg pool + pool_quant + classifier.
// ---------------------------------------------------------------------------
__global__ __launch_bounds__(256) void k_gap_fc(
    const int* __restrict__ a4, const int* __restrict__ qwc,
    const float* __restrict__ bc, const float* __restrict__ scales,
    const float* __restrict__ wscale, float* __restrict__ out)
{
  __shared__ int sh[256][16];
  __shared__ int sq[16];
  int n = blockIdx.x, tid = threadIdx.x;

  int loc[16];
  #pragma unroll
  for (int i = 0; i < 16; i++) loc[i] = 0;
  for (int p = tid; p < 15625; p += 256) {
    int4 v = *(const int4*)(a4 + (n * 15625 + p) * 4);
    int w[4] = {v.x, v.y, v.z, v.w};
    #pragma unroll
    for (int wi = 0; wi < 4; wi++)
      #pragma unroll
      for (int j = 0; j < 4; j++)
        loc[wi * 4 + j] += (int)(signed char)(w[wi] >> (8 * j));
  }
  #pragma unroll
  for (int i = 0; i < 16; i++) sh[tid][i] = loc[i];
  __syncthreads();

  if (tid < 16) {
    int s = 0;
    for (int t = 0; t < 256; t++) s += sh[t][tid];
    float v = scales[9] * (float)s / 15625.0f;
    float r = fminf(fmaxf(rintf(v / scales[10]), -128.0f), 127.0f);
    sq[tid] = (int)r;
  }
  __syncthreads();

  if (tid < 10) {
    int acc = 0;
    #pragma unroll
    for (int k4 = 0; k4 < 4; k4++) {
      int wv = qwc[tid * 4 + k4];
      #pragma unroll
      for (int j = 0; j < 4; j++)
        acc += sq[k4 * 4 + j] * (int)(signed char)(wv >> (8 * j));
    }
    out[n * 10 + tid] = fmaf(scales[10] * wscale[4], (float)acc, bc[tid]);
  }
}

// ---------------------------------------------------------------------------
// Workspace layout (bytes). CORRECTED SIZES (R2 bug: a2p is 68,161,536 B =
// 32*258*258*32, NOT 68,157,440 -> a1 overlapped a2p's last 4 KB).
//   0         wscale (5 floats)
//   64        qw1   144 ints
//   1024      qw2B  1536 ints       (ends 7168)
//   8192      qw3B  6400 ints       (ends 33792)
//   36864     qw4   1152 ints       (ends 41472)
//   43008     qwc   40 ints
//   65536     a2p [32][258][258][32] i8 = 68,161,536 B  -> ends 68,227,072
//             aliased by q0 (2 MB, dead before memset) and a4 (8 MB, conv4+)
//   68227072  a1 [32][254][254][16] i8 = 33,032,192 B   -> ends 101,259,264
//             aliased by a3p [32][127][127][32] i8 = 16,516,096 B (a1 dead)
// Peak 101,259,264 B == R1's proven workspace usage.
// ---------------------------------------------------------------------------
extern "C" void kernel_launch(void* const* d_in, const int* in_sizes, int n_in,
                              void* d_out, int out_size, void* d_ws, size_t ws_size,
                              hipStream_t stream) {
  const float* x  = (const float*)d_in[0];
  const float* w1 = (const float*)d_in[1];
  const float* b1 = (const float*)d_in[2];
  const float* w2 = (const float*)d_in[3];
  const float* b2 = (const float*)d_in[4];
  const float* w3 = (const float*)d_in[5];
  const float* b3 = (const float*)d_in[6];
  const float* w4 = (const float*)d_in[7];
  const float* b4 = (const float*)d_in[8];
  const float* wc = (const float*)d_in[9];
  const float* bc = (const float*)d_in[10];
  const float* sc = (const float*)d_in[11];

  char* ws = (char*)d_ws;
  float* wscale = (float*)(ws + 0);
  int* qw1  = (int*)(ws + 64);
  int* qw2B = (int*)(ws + 1024);
  int* qw3B = (int*)(ws + 8192);
  int* qw4  = (int*)(ws + 36864);
  int* qwc  = (int*)(ws + 43008);
  const size_t SZ_A2P = (size_t)32 * 258 * 258 * 32;   // 68,161,536
  signed char* a2p = (signed char*)(ws + 65536);
  int*  q0  = (int*)(ws + 65536);                      // alias (dead pre-memset)
  int*  a4  = (int*)(ws + 65536);                      // alias (a2p dead by conv4)
  int*  a1  = (int*)(ws + 68227072);
  signed char* a3p = (signed char*)(ws + 68227072);    // alias (a1 dead by conv3)
  float* out = (float*)d_out;

  k_quant_weights<<<5, 256, 0, stream>>>(w1, w2, w3, w4, wc, wscale,
                                         qw1, qw2B, qw3B, qw4, qwc);
  k_quant_input<<<2048, 256, 0, stream>>>(x, sc, q0);
  k_conv1<<<8065, 256, 0, stream>>>((const signed char*)q0, qw1, b1, sc, wscale, a1);
  hipMemsetAsync(a2p, 0, SZ_A2P, stream);
  k_conv2_mfma<<<2048, 256, 0, stream>>>(a1, qw2B, b2, sc, wscale, a2p);
  k_conv3pool_mfma<<<2048, 256, 0, stream>>>(a2p, qw3B, b3, sc, wscale, a3p);
  k_conv4<<<1954, 256, 0, stream>>>((const int*)a3p, qw4, b4, sc, wscale, a4);
  k_gap_fc<<<32, 256, 0, stream>>>(a4, qwc, bc, sc, wscale, out);
}

// Round 5
// 327.982 us; speedup vs baseline: 2.5552x; 1.2819x over previous
//
#include <hip/hip_runtime.h>
#include <math.h>

// ---------------------------------------------------------------------------
// Quantized CNN forward (PaddingNet). conv2/conv3/conv4 on the i8 MFMA pipe;
// conv1 IMAD. Integer conv math exact; quant epilogues use reciprocal-multiply
// (rintf(v*inv_s)) — rare boundary flips are diluted by the global avg pool.
// ---------------------------------------------------------------------------

typedef int i32x4  __attribute__((ext_vector_type(4)));
typedef int i32x16 __attribute__((ext_vector_type(16)));

__device__ __forceinline__ int quant_clip(float v) {
  float r = rintf(v);
  r = fminf(fmaxf(r, -128.0f), 127.0f);
  return (int)r;
}

__device__ __forceinline__ int pack4i8(int q0, int q1, int q2, int q3) {
  return (q0 & 255) | ((q1 & 255) << 8) | ((q2 & 255) << 16) | ((q3 & 255) << 24);
}

// relu -> fq(sA) -> fq(sB) with precomputed reciprocals; returns final code.
// v>=0 after relu so lower clips elided (values provably >= 0).
__device__ __forceinline__ int fq_chain_r(float y, float sA, float invA, float invB) {
  float v  = fmaxf(y, 0.0f);
  float r1 = fminf(rintf(v * invA), 127.0f);
  float rv = r1 * sA;
  float r2 = fminf(rintf(rv * invB), 127.0f);
  return (int)r2;
}

// ---------------------------------------------------------------------------
// Weight quantization + MFMA B-fragment packing.
//  qw1:  [16][9] ints (conv1 IMAD)
//  qw2B: [6 ksteps][64 lanes][4 words]  (kstep = ky*2+kxpair; k = 2 px x 16ic)
//  qw3B: [25 taps][64 lanes][4 words]   (k = 32 ic of one tap)
//  qw4B: [5 mf][64 lanes][4 words]      (16x16x64: k = 2 taps x 32ic, tap9=0)
//  qwc:  [10][4] words
// 32x32 B map: lane l -> col(oc)=l&31, k=(l>>5)*16 + word*4 + byte.
// 16x16 B map: lane l -> col(oc)=l&15, k=(l>>4)*16 + word*4 + byte.
// ---------------------------------------------------------------------------
__global__ __launch_bounds__(256) void k_quant_weights(
    const float* __restrict__ w1, const float* __restrict__ w2,
    const float* __restrict__ w3, const float* __restrict__ w4,
    const float* __restrict__ wc, float* __restrict__ wscale,
    int* __restrict__ qw1, int* __restrict__ qw2B, int* __restrict__ qw3B,
    int* __restrict__ qw4B, int* __restrict__ qwc)
{
  __shared__ float red[256];
  __shared__ float ssh;
  const int t = blockIdx.x, tid = threadIdx.x;
  const float* src = (t == 0) ? w1 : (t == 1) ? w2 : (t == 2) ? w3 : (t == 3) ? w4 : wc;
  const int nsrc   = (t == 0) ? 144 : (t == 1) ? 4608 : (t == 2) ? 25600 : (t == 3) ? 4608 : 160;

  float m = 0.0f;
  for (int i = tid; i < nsrc; i += 256) m = fmaxf(m, fabsf(src[i]));
  red[tid] = m;
  __syncthreads();
  for (int s = 128; s > 0; s >>= 1) {
    if (tid < s) red[tid] = fmaxf(red[tid], red[tid + s]);
    __syncthreads();
  }
  if (tid == 0) { ssh = red[0] / 127.0f; wscale[t] = ssh; }
  __syncthreads();
  const float s = ssh;

  if (t == 0) {
    for (int i = tid; i < 144; i += 256) qw1[i] = quant_clip(w1[i] / s);
  } else if (t == 1) {          // w2 [32][16][3][3] -> 6 ksteps
    for (int wi = tid; wi < 1536; wi += 256) {
      int step = wi >> 8, rem = wi & 255;
      int ln = rem >> 2, w = rem & 3;
      int oc = ln & 31, h = ln >> 5;
      int ky = step >> 1, kxp = (step & 1) * 2;
      int q[4];
      #pragma unroll
      for (int j = 0; j < 4; j++) {
        int k = h * 16 + w * 4 + j;
        int ic = k & 15, kx = kxp + (k >> 4);
        float val = (kx < 3) ? w2[((oc * 16 + ic) * 3 + ky) * 3 + kx] : 0.0f;
        q[j] = quant_clip(val / s);
      }
      qw2B[wi] = pack4i8(q[0], q[1], q[2], q[3]);
    }
  } else if (t == 2) {          // w3 [32][32][5][5] -> 25 taps
    for (int wi = tid; wi < 6400; wi += 256) {
      int tap = wi >> 8, rem = wi & 255;
      int ln = rem >> 2, w = rem & 3;
      int oc = ln & 31, h = ln >> 5;
      int ky = tap / 5, kx = tap % 5;
      int q[4];
      #pragma unroll
      for (int j = 0; j < 4; j++) {
        int ic = h * 16 + w * 4 + j;
        q[j] = quant_clip(w3[((oc * 32 + ic) * 5 + ky) * 5 + kx] / s);
      }
      qw3B[wi] = pack4i8(q[0], q[1], q[2], q[3]);
    }
  } else if (t == 3) {          // w4 [16][32][3][3] -> 5 mf of 16x16x64 B-frags
    for (int wi = tid; wi < 1280; wi += 256) {
      int mf = wi >> 8, rem = wi & 255;
      int ln = rem >> 2, w = rem & 3;
      int oc = ln & 15, chunk = ln >> 4;
      int tp = 2 * mf + (chunk >> 1);
      int half = chunk & 1;
      int q[4];
      #pragma unroll
      for (int j = 0; j < 4; j++) {
        float val = 0.0f;
        if (tp < 9) {
          int ky = tp / 3, kx = tp % 3;
          int ic = half * 16 + w * 4 + j;
          val = w4[((oc * 32 + ic) * 3 + ky) * 3 + kx];
        }
        q[j] = quant_clip(val / s);
      }
      qw4B[wi] = pack4i8(q[0], q[1], q[2], q[3]);
    }
  } else {                      // wc [10][16] -> [10][4]
    for (int wi = tid; wi < 40; wi += 256) {
      int o = wi / 4, i4 = wi % 4;
      int q[4];
      #pragma unroll
      for (int j = 0; j < 4; j++) q[j] = quant_clip(wc[o * 16 + i4 * 4 + j] / s);
      qwc[wi] = pack4i8(q[0], q[1], q[2], q[3]);
    }
  }
}

// ---------------------------------------------------------------------------
// Input fake-quant: x f32 -> int8 packed words (reciprocal-mult).
// ---------------------------------------------------------------------------
__global__ __launch_bounds__(256) void k_quant_input(
    const float* __restrict__ x, const float* __restrict__ scales,
    int* __restrict__ q0w)
{
  int i = blockIdx.x * 256 + threadIdx.x;
  if (i >= 524288) return;
  float inv = 1.0f / scales[0];
  float4 v = ((const float4*)x)[i];
  q0w[i] = pack4i8(quant_clip(v.x * inv), quant_clip(v.y * inv),
                   quant_clip(v.z * inv), quant_clip(v.w * inv));
}

// ---------------------------------------------------------------------------
// Zero a2p's 2-px padding ring (2 MB instead of 68 MB memset).
// 32 img x 2048 border px x 32 B. Border px p: p<1032 -> rows {0,1,256,257};
// else cols {0,1,256,257} of rows 2..255.
// ---------------------------------------------------------------------------
__global__ __launch_bounds__(256) void k_zero_border(int* __restrict__ a2p)
{
  int i = blockIdx.x * 256 + threadIdx.x;     // 65536 threads = 32 x 2048 px
  int n = i >> 11, p = i & 2047;
  int row, col;
  if (p < 1032) {
    int rb = p / 258;
    row = (rb < 2) ? rb : 254 + rb;
    col = p % 258;
  } else {
    int q = p - 1032;
    int cb = q & 3;
    col = (cb < 2) ? cb : 254 + cb;
    row = 2 + (q >> 2);
  }
  int4* dst = (int4*)(a2p + (((size_t)n * 258 + row) * 258 + col) * 8);
  dst[0] = make_int4(0, 0, 0, 0);
  dst[1] = make_int4(0, 0, 0, 0);
}

// ---------------------------------------------------------------------------
// conv1: 1->16ch, 3x3, pad0 (IMAD). Out a1 NHWC [32][254][254][16].
// ---------------------------------------------------------------------------
__global__ __launch_bounds__(256) void k_conv1(
    const signed char* __restrict__ q0, const int* __restrict__ qw1,
    const float* __restrict__ b1, const float* __restrict__ scales,
    const float* __restrict__ wscale, int* __restrict__ a1)
{
  __shared__ int wsh[144];
  if (threadIdx.x < 144) wsh[threadIdx.x] = qw1[threadIdx.x];
  __syncthreads();

  int pix = blockIdx.x * 256 + threadIdx.x;
  const int TOT = 32 * 254 * 254;
  if (pix >= TOT) return;
  int n = pix / (254 * 254), r = pix % (254 * 254);
  int oy = r / 254, ox = r % 254;

  int av[9];
  const signed char* base = q0 + (n * 256 + oy) * 256 + ox;
  #pragma unroll
  for (int ky = 0; ky < 3; ky++)
    #pragma unroll
    for (int kx = 0; kx < 3; kx++)
      av[ky * 3 + kx] = (int)base[ky * 256 + kx];

  float s1 = scales[1], s2 = scales[2];
  float inv1 = 1.0f / s1, inv2 = 1.0f / s2;
  float scl = scales[0] * wscale[0];
  int outw[4];
  #pragma unroll
  for (int g = 0; g < 4; g++) {
    int q[4];
    #pragma unroll
    for (int j = 0; j < 4; j++) {
      int oc = g * 4 + j;
      int acc = 0;
      #pragma unroll
      for (int k = 0; k < 9; k++) acc += av[k] * wsh[oc * 9 + k];
      float y = fmaf(scl, (float)acc, b1[oc]);
      q[j] = fq_chain_r(y, s1, inv1, inv2);
    }
    outw[g] = pack4i8(q[0], q[1], q[2], q[3]);
  }
  *(int4*)(a1 + pix * 4) = make_int4(outw[0], outw[1], outw[2], outw[3]);
}

// ---------------------------------------------------------------------------
// conv2 via MFMA 32x32x32: 16->32ch, 3x3, pad1. M=32 px (1 row), N=32 oc,
// K = 6 steps (2 px x 16 ic). Split accumulators (kp chains) for MFMA ILP.
// Writes zero-padded a2p [32][258][258][32] interior.
// ---------------------------------------------------------------------------
__global__ __launch_bounds__(256) void k_conv2_mfma(
    const int* __restrict__ a1, const int* __restrict__ qw2B,
    const float* __restrict__ b2, const float* __restrict__ scales,
    const float* __restrict__ wscale, signed char* __restrict__ a2p)
{
  const int lane = threadIdx.x & 63;
  const int bid = blockIdx.x;
  const int swz = (bid & 7) * 256 + (bid >> 3);     // XCD-chunked (2048%8==0)
  const int gw = swz * 4 + (threadIdx.x >> 6);

  i32x4 bw[6];
  #pragma unroll
  for (int t = 0; t < 6; t++)
    bw[t] = *(const i32x4*)(qw2B + (t * 64 + lane) * 4);

  const float s3 = scales[3], s4 = scales[4];
  const float inv3 = 1.0f / s3, inv4 = 1.0f / s4;
  const float scl = scales[2] * wscale[1];
  const int oc = lane & 31, h = lane >> 5, rr = lane & 31;
  const float bias = b2[oc];

  const int TILES = 32 * 254 * 8;
  #pragma unroll 1
  for (int t8 = 0; t8 < 8; t8++) {
    int tile = gw * 8 + t8;
    if (tile >= TILES) break;
    int n = tile / (254 * 8);
    int r = tile % (254 * 8);
    int y = r >> 3, X0 = (r & 7) * 32;

    i32x16 acc0, acc1;
    #pragma unroll
    for (int z = 0; z < 16; z++) { acc0[z] = 0; acc1[z] = 0; }

    #pragma unroll
    for (int ky = 0; ky < 3; ky++) {
      int iy = y + ky - 1;
      if (iy < 0 || iy >= 254) continue;            // wave-uniform
      {
        int ix = X0 + rr + h - 1;
        i32x4 a; a[0] = 0; a[1] = 0; a[2] = 0; a[3] = 0;
        if (ix >= 0 && ix < 254)
          a = *(const i32x4*)(a1 + ((n * 254 + iy) * 254 + ix) * 4);
        acc0 = __builtin_amdgcn_mfma_i32_32x32x32_i8(a, bw[ky * 2 + 0], acc0, 0, 0, 0);
      }
      {
        int ix = X0 + rr + 2 + h - 1;
        i32x4 a; a[0] = 0; a[1] = 0; a[2] = 0; a[3] = 0;
        if (ix >= 0 && ix < 254)
          a = *(const i32x4*)(a1 + ((n * 254 + iy) * 254 + ix) * 4);
        acc1 = __builtin_amdgcn_mfma_i32_32x32x32_i8(a, bw[ky * 2 + 1], acc1, 0, 0, 0);
      }
    }

    // C layout: col=lane&31, row=(reg&3)+8*(reg>>2)+4*(lane>>5)
    #pragma unroll
    for (int q = 0; q < 4; q++) {
      #pragma unroll
      for (int j = 0; j < 4; j++) {
        int row = j + 8 * q + 4 * h;
        int x = X0 + row;
        int accv = acc0[q * 4 + j] + acc1[q * 4 + j];
        float yv = fmaf(scl, (float)accv, bias);
        int code = fq_chain_r(yv, s3, inv3, inv4);
        if (x < 254)
          a2p[((size_t)(n * 258 + (y + 2)) * 258 + (x + 2)) * 32 + oc] = (signed char)code;
      }
    }
  }
}

// ---------------------------------------------------------------------------
// conv3 + quant3 + maxpool2x2 + pool_quant via MFMA 32x32x32.
// M=32 conv px = 8 pooled px x (dy,dx); each pool window = one lane reg-quad.
// Max-first pooling: fq chain is monotone, so reduce int accs with v_max
// BEFORE the float quant chain (4 chains instead of 16 per lane).
// launch_bounds(256,2): keep bw[25] (100 VGPR) resident.
// ---------------------------------------------------------------------------
__global__ __launch_bounds__(256, 2) void k_conv3pool_mfma(
    const signed char* __restrict__ a2p, const int* __restrict__ qw3B,
    const float* __restrict__ b3, const float* __restrict__ scales,
    const float* __restrict__ wscale, signed char* __restrict__ a3p)
{
  const int lane = threadIdx.x & 63;
  const int bid = blockIdx.x;
  const int swz = (bid & 7) * 256 + (bid >> 3);
  const int gw = swz * 4 + (threadIdx.x >> 6);

  i32x4 bw[25];
  #pragma unroll
  for (int t = 0; t < 25; t++)
    bw[t] = *(const i32x4*)(qw3B + (t * 64 + lane) * 4);

  const float s5 = scales[5], s6 = scales[6], s7 = scales[7];
  const float inv5 = 1.0f / s5, inv6 = 1.0f / s6, inv7 = 1.0f / s7;
  const float scl = scales[4] * wscale[2];
  const int oc = lane & 31, h = lane >> 5;
  const float bias = b3[oc];

  const int rr = lane & 31;
  const int pp = rr >> 2, dy = (rr >> 1) & 1, dx = rr & 1;

  const int TILES = 32 * 127 * 16;
  #pragma unroll 1
  for (int t8 = 0; t8 < 8; t8++) {
    int tile = gw * 8 + t8;
    if (tile >= TILES) break;
    int n = tile / (127 * 16);
    int r = tile % (127 * 16);
    int Y = r >> 4, X0 = (r & 15) * 8;

    int py = 2 * Y + dy;
    int px = 2 * (X0 + pp) + dx;
    px = min(px, 253);                   // clamp invalid (X>=127) lanes
    const signed char* abase = a2p + ((size_t)(n * 258 + py) * 258 + px) * 32 + h * 16;

    i32x16 acc0, acc1;
    #pragma unroll
    for (int z = 0; z < 16; z++) { acc0[z] = 0; acc1[z] = 0; }

    #pragma unroll
    for (int ky = 0; ky < 5; ky++) {
      const signed char* rb = abase + ky * (258 * 32);
      #pragma unroll
      for (int kx = 0; kx < 5; kx++) {
        int tap = ky * 5 + kx;
        i32x4 a = *(const i32x4*)(rb + kx * 32);
        if (tap < 13)
          acc0 = __builtin_amdgcn_mfma_i32_32x32x32_i8(a, bw[tap], acc0, 0, 0, 0);
        else
          acc1 = __builtin_amdgcn_mfma_i32_32x32x32_i8(a, bw[tap], acc1, 0, 0, 0);
      }
    }

    // pooled block b = 2q + h held as reg-quad q; max-first then quant chain
    #pragma unroll
    for (int q = 0; q < 4; q++) {
      int b = 2 * q + h;
      int X = X0 + b;
      int a0 = acc0[q * 4 + 0] + acc1[q * 4 + 0];
      int a1v = acc0[q * 4 + 1] + acc1[q * 4 + 1];
      int a2 = acc0[q * 4 + 2] + acc1[q * 4 + 2];
      int a3 = acc0[q * 4 + 3] + acc1[q * 4 + 3];
      int am = max(max(a0, a1v), max(a2, a3));
      float yv = fmaf(scl, (float)am, bias);
      float v  = fmaxf(yv, 0.0f);
      float r1 = fminf(rintf(v * inv5), 127.0f);
      float rv = r1 * s5;
      float r2 = fminf(rintf(rv * inv6), 127.0f);   // quant3 code (>=0)
      float pm = r2 * s6;
      float r3 = fminf(rintf(pm * inv7), 127.0f);   // pool_quant code (>=0)
      if (X < 127)
        a3p[((size_t)(n * 127 + Y) * 127 + X) * 32 + oc] = (signed char)(int)r3;
    }
  }
}

// ---------------------------------------------------------------------------
// conv4 via MFMA 16x16x64: 32->16ch, 3x3, pad0. M=16 px (x-run), N=16 oc,
// K = 5 steps of 64 (2 taps x 32 ic; 10th tap zero-weighted, addr clamped).
// In a3p [32][127][127][32] i8. Out a4 bytes [32][125][125][16].
// ---------------------------------------------------------------------------
__global__ __launch_bounds__(256) void k_conv4_mfma(
    const signed char* __restrict__ a3p, const int* __restrict__ qw4B,
    const float* __restrict__ b4, const float* __restrict__ scales,
    const float* __restrict__ wscale, signed char* __restrict__ a4b)
{
  const int lane = threadIdx.x & 63;
  const int bid = blockIdx.x;
  const int swz = (bid & 7) * 256 + (bid >> 3);
  const int gw = swz * 4 + (threadIdx.x >> 6);

  i32x4 bw[5];
  #pragma unroll
  for (int t = 0; t < 5; t++)
    bw[t] = *(const i32x4*)(qw4B + (t * 64 + lane) * 4);

  const int chunk = lane >> 4;
  int offB[5];
  #pragma unroll
  for (int mf = 0; mf < 5; mf++) {
    int tp = 2 * mf + (chunk >> 1);
    if (tp > 8) tp = 8;                 // padded slot: B is zero, clamp addr
    int ky = tp / 3, kx = tp % 3;
    offB[mf] = (ky * 127 + kx) * 32 + (chunk & 1) * 16;
  }

  const float s8 = scales[8], s9 = scales[9];
  const float inv8 = 1.0f / s8, inv9 = 1.0f / s9;
  const float scl = scales[7] * wscale[3];
  const int oc = lane & 15;
  const float bias = b4[oc];
  const int arow = lane & 15;           // A row = input px offset

  const int TILES = 32 * 125 * 8;       // n x y x X0-tiles(16 px)
  #pragma unroll 1
  for (int t4 = 0; t4 < 4; t4++) {
    int tile = gw * 4 + t4;
    if (tile >= TILES) break;
    int n = tile / 1000;
    int r = tile % 1000;
    int y = r >> 3, X0 = (r & 7) * 16;

    const signed char* base =
        a3p + ((size_t)n * 16129 + (size_t)y * 127 + (X0 + arow)) * 32;

    i32x4 acc;
    acc[0] = 0; acc[1] = 0; acc[2] = 0; acc[3] = 0;
    #pragma unroll
    for (int mf = 0; mf < 5; mf++) {
      i32x4 a = *(const i32x4*)(base + offB[mf]);
      acc = __builtin_amdgcn_mfma_i32_16x16x64_i8(a, bw[mf], acc, 0, 0, 0);
    }

    // C 16x16: col=lane&15 (oc), row=(lane>>4)*4+reg (px offset)
    #pragma unroll
    for (int j = 0; j < 4; j++) {
      int x = X0 + chunk * 4 + j;
      float yv = fmaf(scl, (float)acc[j], bias);
      int code = fq_chain_r(yv, s8, inv8, inv9);
      if (x < 125)
        a4b[((size_t)(n * 125 + y) * 125 + x) * 16 + oc] = (signed char)code;
    }
  }
}

// ---------------------------------------------------------------------------
// Global avg pool + pool_quant + classifier (exact divides kept here).
// ---------------------------------------------------------------------------
__global__ __launch_bounds__(256) void k_gap_fc(
    const int* __restrict__ a4, const int* __restrict__ qwc,
    const float* __restrict__ bc, const float* __restrict__ scales,
    const float* __restrict__ wscale, float* __restrict__ out)
{
  __shared__ int sh[256][16];
  __shared__ int sq[16];
  int n = blockIdx.x, tid = threadIdx.x;

  int loc[16];
  #pragma unroll
  for (int i = 0; i < 16; i++) loc[i] = 0;
  for (int p = tid; p < 15625; p += 256) {
    int4 v = *(const int4*)(a4 + (n * 15625 + p) * 4);
    int w[4] = {v.x, v.y, v.z, v.w};
    #pragma unroll
    for (int wi = 0; wi < 4; wi++)
      #pragma unroll
      for (int j = 0; j < 4; j++)
        loc[wi * 4 + j] += (int)(signed char)(w[wi] >> (8 * j));
  }
  #pragma unroll
  for (int i = 0; i < 16; i++) sh[tid][i] = loc[i];
  __syncthreads();

  if (tid < 16) {
    int s = 0;
    for (int t = 0; t < 256; t++) s += sh[t][tid];
    float v = scales[9] * (float)s / 15625.0f;
    float r = fminf(fmaxf(rintf(v / scales[10]), -128.0f), 127.0f);
    sq[tid] = (int)r;
  }
  __syncthreads();

  if (tid < 10) {
    int acc = 0;
    #pragma unroll
    for (int k4 = 0; k4 < 4; k4++) {
      int wv = qwc[tid * 4 + k4];
      #pragma unroll
      for (int j = 0; j < 4; j++)
        acc += sq[k4 * 4 + j] * (int)(signed char)(wv >> (8 * j));
    }
    out[n * 10 + tid] = fmaf(scales[10] * wscale[4], (float)acc, bc[tid]);
  }
}

// ---------------------------------------------------------------------------
// Workspace layout (bytes):
//   0         wscale (5 floats)
//   64        qw1   144 ints
//   1024      qw2B  1536 ints       (ends 7168)
//   8192      qw3B  6400 ints       (ends 33792)
//   36864     qw4B  1280 ints       (ends 41984)
//   43008     qwc   40 ints
//   65536     a2p [32][258][258][32] i8 = 68,161,536 -> ends 68,227,072
//             aliased by q0 (2 MB, dead pre-border-zero) and a4 (8 MB, conv4+)
//   68227072  a1 [32][254][254][16] i8 = 33,032,192 -> ends 101,259,264
//             aliased by a3p (16,516,096; a1 dead by conv3). conv4 A-loads may
//             over-read <=4 KB past a3p end — still inside a1's region.
// Peak 101,259,264 B (== R1/R4 proven usage).
// ---------------------------------------------------------------------------
extern "C" void kernel_launch(void* const* d_in, const int* in_sizes, int n_in,
                              void* d_out, int out_size, void* d_ws, size_t ws_size,
                              hipStream_t stream) {
  const float* x  = (const float*)d_in[0];
  const float* w1 = (const float*)d_in[1];
  const float* b1 = (const float*)d_in[2];
  const float* w2 = (const float*)d_in[3];
  const float* b2 = (const float*)d_in[4];
  const float* w3 = (const float*)d_in[5];
  const float* b3 = (const float*)d_in[6];
  const float* w4 = (const float*)d_in[7];
  const float* b4 = (const float*)d_in[8];
  const float* wc = (const float*)d_in[9];
  const float* bc = (const float*)d_in[10];
  const float* sc = (const float*)d_in[11];

  char* ws = (char*)d_ws;
  float* wscale = (float*)(ws + 0);
  int* qw1  = (int*)(ws + 64);
  int* qw2B = (int*)(ws + 1024);
  int* qw3B = (int*)(ws + 8192);
  int* qw4B = (int*)(ws + 36864);
  int* qwc  = (int*)(ws + 43008);
  signed char* a2p = (signed char*)(ws + 65536);
  int*  q0  = (int*)(ws + 65536);                    // alias (dead pre-border)
  int*  a4  = (int*)(ws + 65536);                    // alias (a2p dead by conv4)
  int*  a1  = (int*)(ws + 68227072);
  signed char* a3p = (signed char*)(ws + 68227072);  // alias (a1 dead by conv3)
  float* out = (float*)d_out;

  k_quant_weights<<<5, 256, 0, stream>>>(w1, w2, w3, w4, wc, wscale,
                                         qw1, qw2B, qw3B, qw4B, qwc);
  k_quant_input<<<2048, 256, 0, stream>>>(x, sc, q0);
  k_conv1<<<8065, 256, 0, stream>>>((const signed char*)q0, qw1, b1, sc, wscale, a1);
  k_zero_border<<<256, 256, 0, stream>>>((int*)a2p);
  k_conv2_mfma<<<2048, 256, 0, stream>>>(a1, qw2B, b2, sc, wscale, a2p);
  k_conv3pool_mfma<<<2048, 256, 0, stream>>>(a2p, qw3B, b3, sc, wscale, a3p);
  k_conv4_mfma<<<2048, 256, 0, stream>>>(a3p, qw4B, b4, sc, wscale,
                                         (signed char*)a4);
  k_gap_fc<<<32, 256, 0, stream>>>(a4, qwc, bc, sc, wscale, out);
}

// Round 6
// 291.811 us; speedup vs baseline: 2.8720x; 1.1240x over previous
//
#include <hip/hip_runtime.h>
#include <math.h>

// ---------------------------------------------------------------------------
// Quantized CNN forward (PaddingNet). conv2/conv3/conv4 on the i8 MFMA pipe;
// conv1 IMAD. Integer conv math exact; quant epilogues via 128-entry LUTs
// (exact: second quant stage depends only on the first-stage code 0..127).
// ---------------------------------------------------------------------------

typedef int i32x4  __attribute__((ext_vector_type(4)));
typedef int i32x16 __attribute__((ext_vector_type(16)));

__device__ __forceinline__ int quant_clip(float v) {
  float r = rintf(v);
  r = fminf(fmaxf(r, -128.0f), 127.0f);
  return (int)r;
}

__device__ __forceinline__ int pack4i8(int q0, int q1, int q2, int q3) {
  return (q0 & 255) | ((q1 & 255) << 8) | ((q2 & 255) << 16) | ((q3 & 255) << 24);
}

// ---------------------------------------------------------------------------
// Weight quantization + MFMA B-fragment packing (unchanged from R5).
// ---------------------------------------------------------------------------
__global__ __launch_bounds__(256) void k_quant_weights(
    const float* __restrict__ w1, const float* __restrict__ w2,
    const float* __restrict__ w3, const float* __restrict__ w4,
    const float* __restrict__ wc, float* __restrict__ wscale,
    int* __restrict__ qw1, int* __restrict__ qw2B, int* __restrict__ qw3B,
    int* __restrict__ qw4B, int* __restrict__ qwc)
{
  __shared__ float red[256];
  __shared__ float ssh;
  const int t = blockIdx.x, tid = threadIdx.x;
  const float* src = (t == 0) ? w1 : (t == 1) ? w2 : (t == 2) ? w3 : (t == 3) ? w4 : wc;
  const int nsrc   = (t == 0) ? 144 : (t == 1) ? 4608 : (t == 2) ? 25600 : (t == 3) ? 4608 : 160;

  float m = 0.0f;
  for (int i = tid; i < nsrc; i += 256) m = fmaxf(m, fabsf(src[i]));
  red[tid] = m;
  __syncthreads();
  for (int s = 128; s > 0; s >>= 1) {
    if (tid < s) red[tid] = fmaxf(red[tid], red[tid + s]);
    __syncthreads();
  }
  if (tid == 0) { ssh = red[0] / 127.0f; wscale[t] = ssh; }
  __syncthreads();
  const float s = ssh;

  if (t == 0) {
    for (int i = tid; i < 144; i += 256) qw1[i] = quant_clip(w1[i] / s);
  } else if (t == 1) {          // w2 [32][16][3][3] -> 6 ksteps
    for (int wi = tid; wi < 1536; wi += 256) {
      int step = wi >> 8, rem = wi & 255;
      int ln = rem >> 2, w = rem & 3;
      int oc = ln & 31, h = ln >> 5;
      int ky = step >> 1, kxp = (step & 1) * 2;
      int q[4];
      #pragma unroll
      for (int j = 0; j < 4; j++) {
        int k = h * 16 + w * 4 + j;
        int ic = k & 15, kx = kxp + (k >> 4);
        float val = (kx < 3) ? w2[((oc * 16 + ic) * 3 + ky) * 3 + kx] : 0.0f;
        q[j] = quant_clip(val / s);
      }
      qw2B[wi] = pack4i8(q[0], q[1], q[2], q[3]);
    }
  } else if (t == 2) {          // w3 [32][32][5][5] -> 25 taps
    for (int wi = tid; wi < 6400; wi += 256) {
      int tap = wi >> 8, rem = wi & 255;
      int ln = rem >> 2, w = rem & 3;
      int oc = ln & 31, h = ln >> 5;
      int ky = tap / 5, kx = tap % 5;
      int q[4];
      #pragma unroll
      for (int j = 0; j < 4; j++) {
        int ic = h * 16 + w * 4 + j;
        q[j] = quant_clip(w3[((oc * 32 + ic) * 5 + ky) * 5 + kx] / s);
      }
      qw3B[wi] = pack4i8(q[0], q[1], q[2], q[3]);
    }
  } else if (t == 3) {          // w4 [16][32][3][3] -> 5 mf of 16x16x64 B-frags
    for (int wi = tid; wi < 1280; wi += 256) {
      int mf = wi >> 8, rem = wi & 255;
      int ln = rem >> 2, w = rem & 3;
      int oc = ln & 15, chunk = ln >> 4;
      int tp = 2 * mf + (chunk >> 1);
      int half = chunk & 1;
      int q[4];
      #pragma unroll
      for (int j = 0; j < 4; j++) {
        float val = 0.0f;
        if (tp < 9) {
          int ky = tp / 3, kx = tp % 3;
          int ic = half * 16 + w * 4 + j;
          val = w4[((oc * 32 + ic) * 3 + ky) * 3 + kx];
        }
        q[j] = quant_clip(val / s);
      }
      qw4B[wi] = pack4i8(q[0], q[1], q[2], q[3]);
    }
  } else {                      // wc [10][16] -> [10][4]
    for (int wi = tid; wi < 40; wi += 256) {
      int o = wi / 4, i4 = wi % 4;
      int q[4];
      #pragma unroll
      for (int j = 0; j < 4; j++) q[j] = quant_clip(wc[o * 16 + i4 * 4 + j] / s);
      qwc[wi] = pack4i8(q[0], q[1], q[2], q[3]);
    }
  }
}

// ---------------------------------------------------------------------------
// Input fake-quant: x f32 -> int8 packed words.
// ---------------------------------------------------------------------------
__global__ __launch_bounds__(256) void k_quant_input(
    const float* __restrict__ x, const float* __restrict__ scales,
    int* __restrict__ q0w)
{
  int i = blockIdx.x * 256 + threadIdx.x;
  if (i >= 524288) return;
  float inv = 1.0f / scales[0];
  float4 v = ((const float4*)x)[i];
  q0w[i] = pack4i8(quant_clip(v.x * inv), quant_clip(v.y * inv),
                   quant_clip(v.z * inv), quant_clip(v.w * inv));
}

// ---------------------------------------------------------------------------
// Zero a2p's 2-px padding ring (2 MB instead of 68 MB memset).
// ---------------------------------------------------------------------------
__global__ __launch_bounds__(256) void k_zero_border(int* __restrict__ a2p)
{
  int i = blockIdx.x * 256 + threadIdx.x;     // 65536 threads = 32 x 2048 px
  int n = i >> 11, p = i & 2047;
  int row, col;
  if (p < 1032) {
    int rb = p / 258;
    row = (rb < 2) ? rb : 254 + rb;
    col = p % 258;
  } else {
    int q = p - 1032;
    int cb = q & 3;
    col = (cb < 2) ? cb : 254 + cb;
    row = 2 + (q >> 2);
  }
  int4* dst = (int4*)(a2p + (((size_t)n * 258 + row) * 258 + col) * 8);
  dst[0] = make_int4(0, 0, 0, 0);
  dst[1] = make_int4(0, 0, 0, 0);
}

// ---------------------------------------------------------------------------
// conv1: 1->16ch, 3x3, pad0 (IMAD) + LUT epilogue. Out a1 NHWC.
// ---------------------------------------------------------------------------
__global__ __launch_bounds__(256) void k_conv1(
    const signed char* __restrict__ q0, const int* __restrict__ qw1,
    const float* __restrict__ b1, const float* __restrict__ scales,
    const float* __restrict__ wscale, int* __restrict__ a1)
{
  __shared__ int wsh[144];
  __shared__ signed char lut[128];
  if (threadIdx.x < 144) wsh[threadIdx.x] = qw1[threadIdx.x];
  if (threadIdx.x < 128) {
    float s1 = scales[1], inv2 = 1.0f / scales[2];
    lut[threadIdx.x] =
        (signed char)(int)fminf(rintf(((float)threadIdx.x * s1) * inv2), 127.0f);
  }
  __syncthreads();

  int pix = blockIdx.x * 256 + threadIdx.x;
  const int TOT = 32 * 254 * 254;
  if (pix >= TOT) return;
  int n = pix / (254 * 254), r = pix % (254 * 254);
  int oy = r / 254, ox = r % 254;

  int av[9];
  const signed char* base = q0 + (n * 256 + oy) * 256 + ox;
  #pragma unroll
  for (int ky = 0; ky < 3; ky++)
    #pragma unroll
    for (int kx = 0; kx < 3; kx++)
      av[ky * 3 + kx] = (int)base[ky * 256 + kx];

  float inv1 = 1.0f / scales[1];
  float scl = scales[0] * wscale[0];
  int outw[4];
  #pragma unroll
  for (int g = 0; g < 4; g++) {
    int q[4];
    #pragma unroll
    for (int j = 0; j < 4; j++) {
      int oc = g * 4 + j;
      int acc = 0;
      #pragma unroll
      for (int k = 0; k < 9; k++) acc += av[k] * wsh[oc * 9 + k];
      float y = fmaf(scl, (float)acc, b1[oc]);
      int idx = (int)fminf(fmaxf(rintf(y * inv1), 0.0f), 127.0f);
      q[j] = lut[idx];
    }
    outw[g] = pack4i8(q[0], q[1], q[2], q[3]);
  }
  *(int4*)(a1 + pix * 4) = make_int4(outw[0], outw[1], outw[2], outw[3]);
}

// ---------------------------------------------------------------------------
// conv2 via MFMA 32x32x32. Batched A loads (clamped addr + mask-zero) before
// the 6-MFMA chain; LUT epilogue. Writes padded a2p interior.
// ---------------------------------------------------------------------------
__global__ __launch_bounds__(256) void k_conv2_mfma(
    const int* __restrict__ a1, const int* __restrict__ qw2B,
    const float* __restrict__ b2, const float* __restrict__ scales,
    const float* __restrict__ wscale, signed char* __restrict__ a2p)
{
  __shared__ signed char lut[128];
  if (threadIdx.x < 128) {
    float s3 = scales[3], inv4 = 1.0f / scales[4];
    lut[threadIdx.x] =
        (signed char)(int)fminf(rintf(((float)threadIdx.x * s3) * inv4), 127.0f);
  }
  __syncthreads();

  const int lane = threadIdx.x & 63;
  const int bid = blockIdx.x;
  const int swz = (bid & 7) * 256 + (bid >> 3);     // XCD-chunked (2048%8==0)
  const int gw = swz * 4 + (threadIdx.x >> 6);

  i32x4 bw[6];
  #pragma unroll
  for (int t = 0; t < 6; t++)
    bw[t] = *(const i32x4*)(qw2B + (t * 64 + lane) * 4);

  const float inv3 = 1.0f / scales[3];
  const float scl = scales[2] * wscale[1];
  const int oc = lane & 31, h = lane >> 5, rr = lane & 31;
  const float bias = b2[oc];

  const int TILES = 32 * 254 * 8;
  #pragma unroll 1
  for (int t8 = 0; t8 < 8; t8++) {
    int tile = gw * 8 + t8;
    if (tile >= TILES) break;
    int n = tile / (254 * 8);
    int r = tile % (254 * 8);
    int y = r >> 3, X0 = (r & 7) * 32;

    // batch all 6 A-fragment loads (one latency wall), then mask-zero
    i32x4 Af[6];
    #pragma unroll
    for (int ky = 0; ky < 3; ky++) {
      int iy = y + ky - 1;
      bool vy = (iy >= 0) && (iy < 254);
      int iyc = min(max(iy, 0), 253);
      #pragma unroll
      for (int kp = 0; kp < 2; kp++) {
        int ix = X0 + rr + kp * 2 + h - 1;
        bool vx = (ix >= 0) && (ix < 254);
        int ixc = min(max(ix, 0), 253);
        i32x4 a = *(const i32x4*)(a1 + ((n * 254 + iyc) * 254 + ixc) * 4);
        bool v = vy && vx;
        i32x4 z;
        z[0] = v ? a[0] : 0; z[1] = v ? a[1] : 0;
        z[2] = v ? a[2] : 0; z[3] = v ? a[3] : 0;
        Af[ky * 2 + kp] = z;
      }
    }

    i32x16 acc0, acc1;
    #pragma unroll
    for (int z = 0; z < 16; z++) { acc0[z] = 0; acc1[z] = 0; }
    #pragma unroll
    for (int ky = 0; ky < 3; ky++) {
      acc0 = __builtin_amdgcn_mfma_i32_32x32x32_i8(Af[ky * 2 + 0], bw[ky * 2 + 0], acc0, 0, 0, 0);
      acc1 = __builtin_amdgcn_mfma_i32_32x32x32_i8(Af[ky * 2 + 1], bw[ky * 2 + 1], acc1, 0, 0, 0);
    }

    // C layout: col=lane&31, row=(reg&3)+8*(reg>>2)+4*(lane>>5)
    #pragma unroll
    for (int q = 0; q < 4; q++) {
      #pragma unroll
      for (int j = 0; j < 4; j++) {
        int row = j + 8 * q + 4 * h;
        int x = X0 + row;
        int accv = acc0[q * 4 + j] + acc1[q * 4 + j];
        float yv = fmaf(scl, (float)accv, bias);
        int idx = (int)fminf(fmaxf(rintf(yv * inv3), 0.0f), 127.0f);
        if (x < 254)
          a2p[((size_t)(n * 258 + (y + 2)) * 258 + (x + 2)) * 32 + oc] =
              lut[idx];
      }
    }
  }
}

// ---------------------------------------------------------------------------
// conv3 + quant3 + maxpool2x2 + pool_quant via MFMA 32x32x32.
// B-fragments in LDS (ds_read_b128, conflict-free); A register-pipelined one
// ky-row ahead. Max-first pooling (monotone chain) + two LUTs.
// launch_bounds(256,4): ~100 VGPR -> 4 waves/SIMD.
// ---------------------------------------------------------------------------
__global__ __launch_bounds__(256, 4) void k_conv3pool_mfma(
    const signed char* __restrict__ a2p, const int* __restrict__ qw3B,
    const float* __restrict__ b3, const float* __restrict__ scales,
    const float* __restrict__ wscale, signed char* __restrict__ a3p)
{
  __shared__ int bsh[6400];                 // [25 taps][64 lanes][4 words]
  __shared__ signed char lut56[128];
  __shared__ signed char lut67[128];
  {
    const int tid = threadIdx.x;
    for (int i = tid; i < 6400; i += 256) bsh[i] = qw3B[i];
    if (tid < 128) {
      float s5 = scales[5], s6 = scales[6];
      float inv6 = 1.0f / s6, inv7 = 1.0f / scales[7];
      lut56[tid] = (signed char)(int)fminf(rintf(((float)tid * s5) * inv6), 127.0f);
      lut67[tid] = (signed char)(int)fminf(rintf(((float)tid * s6) * inv7), 127.0f);
    }
  }
  __syncthreads();

  const int lane = threadIdx.x & 63;
  const int bid = blockIdx.x;
  const int swz = (bid & 7) * 256 + (bid >> 3);
  const int gw = swz * 4 + (threadIdx.x >> 6);

  const float inv5 = 1.0f / scales[5];
  const float scl = scales[4] * wscale[2];
  const int oc = lane & 31, h = lane >> 5;
  const float bias = b3[oc];

  const int rr = lane & 31;
  const int pp = rr >> 2, dy = (rr >> 1) & 1, dx = rr & 1;

  const int TILES = 32 * 127 * 16;
  #pragma unroll 1
  for (int t8 = 0; t8 < 8; t8++) {
    int tile = gw * 8 + t8;
    if (tile >= TILES) break;
    int n = tile / (127 * 16);
    int r = tile % (127 * 16);
    int Y = r >> 4, X0 = (r & 15) * 8;

    int py = 2 * Y + dy;
    int px = 2 * (X0 + pp) + dx;
    px = min(px, 253);                   // clamp invalid (X>=127) lanes
    const signed char* abase = a2p + ((size_t)(n * 258 + py) * 258 + px) * 32 + h * 16;

    i32x16 acc0, acc1;
    #pragma unroll
    for (int z = 0; z < 16; z++) { acc0[z] = 0; acc1[z] = 0; }

    // software-pipelined: A row ky+1 loads in flight over row ky's MFMAs
    i32x4 A0[5], A1[5];
    #pragma unroll
    for (int kx = 0; kx < 5; kx++)
      A0[kx] = *(const i32x4*)(abase + kx * 32);

    #pragma unroll
    for (int ky = 0; ky < 5; ky++) {
      if (ky < 4) {
        const signed char* rbn = abase + (ky + 1) * (258 * 32);
        #pragma unroll
        for (int kx = 0; kx < 5; kx++)
          A1[kx] = *(const i32x4*)(rbn + kx * 32);
      }
      #pragma unroll
      for (int kx = 0; kx < 5; kx++) {
        int tap = ky * 5 + kx;
        i32x4 b = *(const i32x4*)&bsh[(tap * 64 + lane) * 4];
        if (tap & 1)
          acc1 = __builtin_amdgcn_mfma_i32_32x32x32_i8(A0[kx], b, acc1, 0, 0, 0);
        else
          acc0 = __builtin_amdgcn_mfma_i32_32x32x32_i8(A0[kx], b, acc0, 0, 0, 0);
      }
      if (ky < 4) {
        #pragma unroll
        for (int kx = 0; kx < 5; kx++) A0[kx] = A1[kx];
      }
    }

    // pooled block b = 2q + h held as reg-quad q; max-first then LUT chain
    #pragma unroll
    for (int q = 0; q < 4; q++) {
      int b = 2 * q + h;
      int X = X0 + b;
      int a0 = acc0[q * 4 + 0] + acc1[q * 4 + 0];
      int a1v = acc0[q * 4 + 1] + acc1[q * 4 + 1];
      int a2 = acc0[q * 4 + 2] + acc1[q * 4 + 2];
      int a3 = acc0[q * 4 + 3] + acc1[q * 4 + 3];
      int am = max(max(a0, a1v), max(a2, a3));
      float yv = fmaf(scl, (float)am, bias);
      int r1 = (int)fminf(fmaxf(rintf(yv * inv5), 0.0f), 127.0f);
      int r2 = lut56[r1];
      int r3 = lut67[r2];
      if (X < 127)
        a3p[((size_t)(n * 127 + Y) * 127 + X) * 32 + oc] = (signed char)r3;
    }
  }
}

// ---------------------------------------------------------------------------
// conv4 via MFMA 16x16x64. Batched 5 A-loads before the MFMA chain; LUT
// epilogue. In a3p; out a4 bytes [32][125][125][16].
// ---------------------------------------------------------------------------
__global__ __launch_bounds__(256) void k_conv4_mfma(
    const signed char* __restrict__ a3p, const int* __restrict__ qw4B,
    const float* __restrict__ b4, const float* __restrict__ scales,
    const float* __restrict__ wscale, signed char* __restrict__ a4b)
{
  __shared__ signed char lut[128];
  if (threadIdx.x < 128) {
    float s8 = scales[8], inv9 = 1.0f / scales[9];
    lut[threadIdx.x] =
        (signed char)(int)fminf(rintf(((float)threadIdx.x * s8) * inv9), 127.0f);
  }
  __syncthreads();

  const int lane = threadIdx.x & 63;
  const int bid = blockIdx.x;
  const int swz = (bid & 7) * 256 + (bid >> 3);
  const int gw = swz * 4 + (threadIdx.x >> 6);

  i32x4 bw[5];
  #pragma unroll
  for (int t = 0; t < 5; t++)
    bw[t] = *(const i32x4*)(qw4B + (t * 64 + lane) * 4);

  const int chunk = lane >> 4;
  int offB[5];
  #pragma unroll
  for (int mf = 0; mf < 5; mf++) {
    int tp = 2 * mf + (chunk >> 1);
    if (tp > 8) tp = 8;                 // padded slot: B is zero, clamp addr
    int ky = tp / 3, kx = tp % 3;
    offB[mf] = (ky * 127 + kx) * 32 + (chunk & 1) * 16;
  }

  const float inv8 = 1.0f / scales[8];
  const float scl = scales[7] * wscale[3];
  const int oc = lane & 15;
  const float bias = b4[oc];
  const int arow = lane & 15;

  const int TILES = 32 * 125 * 8;
  #pragma unroll 1
  for (int t4 = 0; t4 < 4; t4++) {
    int tile = gw * 4 + t4;
    if (tile >= TILES) break;
    int n = tile / 1000;
    int r = tile % 1000;
    int y = r >> 3, X0 = (r & 7) * 16;

    const signed char* base =
        a3p + ((size_t)n * 16129 + (size_t)y * 127 + (X0 + arow)) * 32;

    i32x4 Af[5];
    #pragma unroll
    for (int mf = 0; mf < 5; mf++)
      Af[mf] = *(const i32x4*)(base + offB[mf]);

    i32x4 acc;
    acc[0] = 0; acc[1] = 0; acc[2] = 0; acc[3] = 0;
    #pragma unroll
    for (int mf = 0; mf < 5; mf++)
      acc = __builtin_amdgcn_mfma_i32_16x16x64_i8(Af[mf], bw[mf], acc, 0, 0, 0);

    // C 16x16: col=lane&15 (oc), row=(lane>>4)*4+reg (px offset)
    #pragma unroll
    for (int j = 0; j < 4; j++) {
      int x = X0 + chunk * 4 + j;
      float yv = fmaf(scl, (float)acc[j], bias);
      int idx = (int)fminf(fmaxf(rintf(yv * inv8), 0.0f), 127.0f);
      if (x < 125)
        a4b[((size_t)(n * 125 + y) * 125 + x) * 16 + oc] = lut[idx];
    }
  }
}

// ---------------------------------------------------------------------------
// GAP stage: 512 blocks (16 chunks/img) wave-reduce + atomicAdd int partials.
// ---------------------------------------------------------------------------
__global__ __launch_bounds__(256) void k_gap_stage(
    const int* __restrict__ a4, int* __restrict__ gap_acc)
{
  int img = blockIdx.x >> 4, chunk = blockIdx.x & 15;
  int tid = threadIdx.x, lane = tid & 63;
  int p0 = chunk * 977, p1 = min(p0 + 977, 15625);

  int loc[16];
  #pragma unroll
  for (int i = 0; i < 16; i++) loc[i] = 0;
  for (int p = p0 + tid; p < p1; p += 256) {
    int4 v = *(const int4*)(a4 + (img * 15625 + p) * 4);
    int w[4] = {v.x, v.y, v.z, v.w};
    #pragma unroll
    for (int wi = 0; wi < 4; wi++)
      #pragma unroll
      for (int j = 0; j < 4; j++)
        loc[wi * 4 + j] += (int)(signed char)(w[wi] >> (8 * j));
  }
  #pragma unroll
  for (int c = 0; c < 16; c++) {
    #pragma unroll
    for (int off = 32; off > 0; off >>= 1)
      loc[c] += __shfl_down(loc[c], off);
  }
  if (lane == 0) {
    #pragma unroll
    for (int c = 0; c < 16; c++) atomicAdd(&gap_acc[img * 16 + c], loc[c]);
  }
}

// ---------------------------------------------------------------------------
// pool_quant + classifier from GAP partials. 32 blocks x 64 thr.
// ---------------------------------------------------------------------------
__global__ __launch_bounds__(64) void k_fc(
    const int* __restrict__ gap_acc, const int* __restrict__ qwc,
    const float* __restrict__ bc, const float* __restrict__ scales,
    const float* __restrict__ wscale, float* __restrict__ out)
{
  __shared__ int sq[16];
  int n = blockIdx.x, tid = threadIdx.x;
  if (tid < 16) {
    int s = gap_acc[n * 16 + tid];
    float v = scales[9] * (float)s / 15625.0f;
    float r = fminf(fmaxf(rintf(v / scales[10]), -128.0f), 127.0f);
    sq[tid] = (int)r;
  }
  __syncthreads();
  if (tid < 10) {
    int acc = 0;
    #pragma unroll
    for (int k4 = 0; k4 < 4; k4++) {
      int wv = qwc[tid * 4 + k4];
      #pragma unroll
      for (int j = 0; j < 4; j++)
        acc += sq[k4 * 4 + j] * (int)(signed char)(wv >> (8 * j));
    }
    out[n * 10 + tid] = fmaf(scales[10] * wscale[4], (float)acc, bc[tid]);
  }
}

// ---------------------------------------------------------------------------
// Workspace layout (bytes), peak 101,259,264 (proven):
//   0         wscale (5 floats)
//   64        qw1   144 ints
//   1024      qw2B  1536 ints
//   8192      qw3B  6400 ints
//   36864     qw4B  1280 ints
//   43008     qwc   40 ints
//   49152     gap_acc 512 ints (2 KB, memset each launch)
//   65536     a2p [32][258][258][32] i8 = 68,161,536 -> ends 68,227,072
//             aliased by q0 (2 MB, dead pre-border-zero) and a4 (8 MB, conv4+)
//   68227072  a1 [32][254][254][16] i8 = 33,032,192 -> ends 101,259,264
//             aliased by a3p (16,516,096; a1 dead by conv3)
// ---------------------------------------------------------------------------
extern "C" void kernel_launch(void* const* d_in, const int* in_sizes, int n_in,
                              void* d_out, int out_size, void* d_ws, size_t ws_size,
                              hipStream_t stream) {
  const float* x  = (const float*)d_in[0];
  const float* w1 = (const float*)d_in[1];
  const float* b1 = (const float*)d_in[2];
  const float* w2 = (const float*)d_in[3];
  const float* b2 = (const float*)d_in[4];
  const float* w3 = (const float*)d_in[5];
  const float* b3 = (const float*)d_in[6];
  const float* w4 = (const float*)d_in[7];
  const float* b4 = (const float*)d_in[8];
  const float* wc = (const float*)d_in[9];
  const float* bc = (const float*)d_in[10];
  const float* sc = (const float*)d_in[11];

  char* ws = (char*)d_ws;
  float* wscale = (float*)(ws + 0);
  int* qw1  = (int*)(ws + 64);
  int* qw2B = (int*)(ws + 1024);
  int* qw3B = (int*)(ws + 8192);
  int* qw4B = (int*)(ws + 36864);
  int* qwc  = (int*)(ws + 43008);
  int* gap_acc = (int*)(ws + 49152);
  signed char* a2p = (signed char*)(ws + 65536);
  int*  q0  = (int*)(ws + 65536);                    // alias (dead pre-border)
  int*  a4  = (int*)(ws + 65536);                    // alias (a2p dead by conv4)
  int*  a1  = (int*)(ws + 68227072);
  signed char* a3p = (signed char*)(ws + 68227072);  // alias (a1 dead by conv3)
  float* out = (float*)d_out;

  hipMemsetAsync(gap_acc, 0, 2048, stream);
  k_quant_weights<<<5, 256, 0, stream>>>(w1, w2, w3, w4, wc, wscale,
                                         qw1, qw2B, qw3B, qw4B, qwc);
  k_quant_input<<<2048, 256, 0, stream>>>(x, sc, q0);
  k_conv1<<<8065, 256, 0, stream>>>((const signed char*)q0, qw1, b1, sc, wscale, a1);
  k_zero_border<<<256, 256, 0, stream>>>((int*)a2p);
  k_conv2_mfma<<<2048, 256, 0, stream>>>(a1, qw2B, b2, sc, wscale, a2p);
  k_conv3pool_mfma<<<2048, 256, 0, stream>>>(a2p, qw3B, b3, sc, wscale, a3p);
  k_conv4_mfma<<<2048, 256, 0, stream>>>(a3p, qw4B, b4, sc, wscale,
                                         (signed char*)a4);
  k_gap_stage<<<512, 256, 0, stream>>>(a4, gap_acc);
  k_fc<<<32, 64, 0, stream>>>(gap_acc, qwc, bc, sc, wscale, out);
}

// Round 7
// 279.092 us; speedup vs baseline: 3.0028x; 1.0456x over previous
//
#include <hip/hip_runtime.h>
#include <math.h>

// ---------------------------------------------------------------------------
// Quantized CNN forward (PaddingNet). conv2/conv3/conv4 on the i8 MFMA pipe;
// conv1 IMAD. Integer conv math exact; quant epilogues via 128-entry LUTs.
// conv3: LDS-staged 2-phase schedule, ty-pair tiles, shared-B taps, rolling
// A-row register window.
// ---------------------------------------------------------------------------

typedef int i32x4  __attribute__((ext_vector_type(4)));
typedef int i32x16 __attribute__((ext_vector_type(16)));

__device__ __forceinline__ int quant_clip(float v) {
  float r = rintf(v);
  r = fminf(fmaxf(r, -128.0f), 127.0f);
  return (int)r;
}

__device__ __forceinline__ int pack4i8(int q0, int q1, int q2, int q3) {
  return (q0 & 255) | ((q1 & 255) << 8) | ((q2 & 255) << 16) | ((q3 & 255) << 24);
}

// ---------------------------------------------------------------------------
// Weight quantization + MFMA B-fragment packing (unchanged, proven).
// ---------------------------------------------------------------------------
__global__ __launch_bounds__(256) void k_quant_weights(
    const float* __restrict__ w1, const float* __restrict__ w2,
    const float* __restrict__ w3, const float* __restrict__ w4,
    const float* __restrict__ wc, float* __restrict__ wscale,
    int* __restrict__ qw1, int* __restrict__ qw2B, int* __restrict__ qw3B,
    int* __restrict__ qw4B, int* __restrict__ qwc)
{
  __shared__ float red[256];
  __shared__ float ssh;
  const int t = blockIdx.x, tid = threadIdx.x;
  const float* src = (t == 0) ? w1 : (t == 1) ? w2 : (t == 2) ? w3 : (t == 3) ? w4 : wc;
  const int nsrc   = (t == 0) ? 144 : (t == 1) ? 4608 : (t == 2) ? 25600 : (t == 3) ? 4608 : 160;

  float m = 0.0f;
  for (int i = tid; i < nsrc; i += 256) m = fmaxf(m, fabsf(src[i]));
  red[tid] = m;
  __syncthreads();
  for (int s = 128; s > 0; s >>= 1) {
    if (tid < s) red[tid] = fmaxf(red[tid], red[tid + s]);
    __syncthreads();
  }
  if (tid == 0) { ssh = red[0] / 127.0f; wscale[t] = ssh; }
  __syncthreads();
  const float s = ssh;

  if (t == 0) {
    for (int i = tid; i < 144; i += 256) qw1[i] = quant_clip(w1[i] / s);
  } else if (t == 1) {          // w2 [32][16][3][3] -> 6 ksteps
    for (int wi = tid; wi < 1536; wi += 256) {
      int step = wi >> 8, rem = wi & 255;
      int ln = rem >> 2, w = rem & 3;
      int oc = ln & 31, h = ln >> 5;
      int ky = step >> 1, kxp = (step & 1) * 2;
      int q[4];
      #pragma unroll
      for (int j = 0; j < 4; j++) {
        int k = h * 16 + w * 4 + j;
        int ic = k & 15, kx = kxp + (k >> 4);
        float val = (kx < 3) ? w2[((oc * 16 + ic) * 3 + ky) * 3 + kx] : 0.0f;
        q[j] = quant_clip(val / s);
      }
      qw2B[wi] = pack4i8(q[0], q[1], q[2], q[3]);
    }
  } else if (t == 2) {          // w3 [32][32][5][5] -> 25 taps
    for (int wi = tid; wi < 6400; wi += 256) {
      int tap = wi >> 8, rem = wi & 255;
      int ln = rem >> 2, w = rem & 3;
      int oc = ln & 31, h = ln >> 5;
      int ky = tap / 5, kx = tap % 5;
      int q[4];
      #pragma unroll
      for (int j = 0; j < 4; j++) {
        int ic = h * 16 + w * 4 + j;
        q[j] = quant_clip(w3[((oc * 32 + ic) * 5 + ky) * 5 + kx] / s);
      }
      qw3B[wi] = pack4i8(q[0], q[1], q[2], q[3]);
    }
  } else if (t == 3) {          // w4 [16][32][3][3] -> 5 mf of 16x16x64 B-frags
    for (int wi = tid; wi < 1280; wi += 256) {
      int mf = wi >> 8, rem = wi & 255;
      int ln = rem >> 2, w = rem & 3;
      int oc = ln & 15, chunk = ln >> 4;
      int tp = 2 * mf + (chunk >> 1);
      int half = chunk & 1;
      int q[4];
      #pragma unroll
      for (int j = 0; j < 4; j++) {
        float val = 0.0f;
        if (tp < 9) {
          int ky = tp / 3, kx = tp % 3;
          int ic = half * 16 + w * 4 + j;
          val = w4[((oc * 32 + ic) * 3 + ky) * 3 + kx];
        }
        q[j] = quant_clip(val / s);
      }
      qw4B[wi] = pack4i8(q[0], q[1], q[2], q[3]);
    }
  } else {                      // wc [10][16] -> [10][4]
    for (int wi = tid; wi < 40; wi += 256) {
      int o = wi / 4, i4 = wi % 4;
      int q[4];
      #pragma unroll
      for (int j = 0; j < 4; j++) q[j] = quant_clip(wc[o * 16 + i4 * 4 + j] / s);
      qwc[wi] = pack4i8(q[0], q[1], q[2], q[3]);
    }
  }
}

// ---------------------------------------------------------------------------
// Input fake-quant.
// ---------------------------------------------------------------------------
__global__ __launch_bounds__(256) void k_quant_input(
    const float* __restrict__ x, const float* __restrict__ scales,
    int* __restrict__ q0w)
{
  int i = blockIdx.x * 256 + threadIdx.x;
  if (i >= 524288) return;
  float inv = 1.0f / scales[0];
  float4 v = ((const float4*)x)[i];
  q0w[i] = pack4i8(quant_clip(v.x * inv), quant_clip(v.y * inv),
                   quant_clip(v.z * inv), quant_clip(v.w * inv));
}

// ---------------------------------------------------------------------------
// Zero a2p's 2-px padding ring.
// ---------------------------------------------------------------------------
__global__ __launch_bounds__(256) void k_zero_border(int* __restrict__ a2p)
{
  int i = blockIdx.x * 256 + threadIdx.x;     // 65536 threads = 32 x 2048 px
  int n = i >> 11, p = i & 2047;
  int row, col;
  if (p < 1032) {
    int rb = p / 258;
    row = (rb < 2) ? rb : 254 + rb;
    col = p % 258;
  } else {
    int q = p - 1032;
    int cb = q & 3;
    col = (cb < 2) ? cb : 254 + cb;
    row = 2 + (q >> 2);
  }
  int4* dst = (int4*)(a2p + (((size_t)n * 258 + row) * 258 + col) * 8);
  dst[0] = make_int4(0, 0, 0, 0);
  dst[1] = make_int4(0, 0, 0, 0);
}

// ---------------------------------------------------------------------------
// conv1: 1->16ch, 3x3, pad0 (IMAD) + LUT epilogue.
// ---------------------------------------------------------------------------
__global__ __launch_bounds__(256) void k_conv1(
    const signed char* __restrict__ q0, const int* __restrict__ qw1,
    const float* __restrict__ b1, const float* __restrict__ scales,
    const float* __restrict__ wscale, int* __restrict__ a1)
{
  __shared__ int wsh[144];
  __shared__ signed char lut[128];
  if (threadIdx.x < 144) wsh[threadIdx.x] = qw1[threadIdx.x];
  if (threadIdx.x < 128) {
    float s1 = scales[1], inv2 = 1.0f / scales[2];
    lut[threadIdx.x] =
        (signed char)(int)fminf(rintf(((float)threadIdx.x * s1) * inv2), 127.0f);
  }
  __syncthreads();

  int pix = blockIdx.x * 256 + threadIdx.x;
  const int TOT = 32 * 254 * 254;
  if (pix >= TOT) return;
  int n = pix / (254 * 254), r = pix % (254 * 254);
  int oy = r / 254, ox = r % 254;

  int av[9];
  const signed char* base = q0 + (n * 256 + oy) * 256 + ox;
  #pragma unroll
  for (int ky = 0; ky < 3; ky++)
    #pragma unroll
    for (int kx = 0; kx < 3; kx++)
      av[ky * 3 + kx] = (int)base[ky * 256 + kx];

  float inv1 = 1.0f / scales[1];
  float scl = scales[0] * wscale[0];
  int outw[4];
  #pragma unroll
  for (int g = 0; g < 4; g++) {
    int q[4];
    #pragma unroll
    for (int j = 0; j < 4; j++) {
      int oc = g * 4 + j;
      int acc = 0;
      #pragma unroll
      for (int k = 0; k < 9; k++) acc += av[k] * wsh[oc * 9 + k];
      float y = fmaf(scl, (float)acc, b1[oc]);
      int idx = (int)fminf(fmaxf(rintf(y * inv1), 0.0f), 127.0f);
      q[j] = lut[idx];
    }
    outw[g] = pack4i8(q[0], q[1], q[2], q[3]);
  }
  *(int4*)(a1 + pix * 4) = make_int4(outw[0], outw[1], outw[2], outw[3]);
}

// ---------------------------------------------------------------------------
// conv2 via MFMA 32x32x32 (unchanged from R6, proven).
// ---------------------------------------------------------------------------
__global__ __launch_bounds__(256) void k_conv2_mfma(
    const int* __restrict__ a1, const int* __restrict__ qw2B,
    const float* __restrict__ b2, const float* __restrict__ scales,
    const float* __restrict__ wscale, signed char* __restrict__ a2p)
{
  __shared__ signed char lut[128];
  if (threadIdx.x < 128) {
    float s3 = scales[3], inv4 = 1.0f / scales[4];
    lut[threadIdx.x] =
        (signed char)(int)fminf(rintf(((float)threadIdx.x * s3) * inv4), 127.0f);
  }
  __syncthreads();

  const int lane = threadIdx.x & 63;
  const int bid = blockIdx.x;
  const int swz = (bid & 7) * 256 + (bid >> 3);     // XCD-chunked (2048%8==0)
  const int gw = swz * 4 + (threadIdx.x >> 6);

  i32x4 bw[6];
  #pragma unroll
  for (int t = 0; t < 6; t++)
    bw[t] = *(const i32x4*)(qw2B + (t * 64 + lane) * 4);

  const float inv3 = 1.0f / scales[3];
  const float scl = scales[2] * wscale[1];
  const int oc = lane & 31, h = lane >> 5, rr = lane & 31;
  const float bias = b2[oc];

  const int TILES = 32 * 254 * 8;
  #pragma unroll 1
  for (int t8 = 0; t8 < 8; t8++) {
    int tile = gw * 8 + t8;
    if (tile >= TILES) break;
    int n = tile / (254 * 8);
    int r = tile % (254 * 8);
    int y = r >> 3, X0 = (r & 7) * 32;

    i32x4 Af[6];
    #pragma unroll
    for (int ky = 0; ky < 3; ky++) {
      int iy = y + ky - 1;
      bool vy = (iy >= 0) && (iy < 254);
      int iyc = min(max(iy, 0), 253);
      #pragma unroll
      for (int kp = 0; kp < 2; kp++) {
        int ix = X0 + rr + kp * 2 + h - 1;
        bool vx = (ix >= 0) && (ix < 254);
        int ixc = min(max(ix, 0), 253);
        i32x4 a = *(const i32x4*)(a1 + ((n * 254 + iyc) * 254 + ixc) * 4);
        bool v = vy && vx;
        i32x4 z;
        z[0] = v ? a[0] : 0; z[1] = v ? a[1] : 0;
        z[2] = v ? a[2] : 0; z[3] = v ? a[3] : 0;
        Af[ky * 2 + kp] = z;
      }
    }

    i32x16 acc0, acc1;
    #pragma unroll
    for (int z = 0; z < 16; z++) { acc0[z] = 0; acc1[z] = 0; }
    #pragma unroll
    for (int ky = 0; ky < 3; ky++) {
      acc0 = __builtin_amdgcn_mfma_i32_32x32x32_i8(Af[ky * 2 + 0], bw[ky * 2 + 0], acc0, 0, 0, 0);
      acc1 = __builtin_amdgcn_mfma_i32_32x32x32_i8(Af[ky * 2 + 1], bw[ky * 2 + 1], acc1, 0, 0, 0);
    }

    #pragma unroll
    for (int q = 0; q < 4; q++) {
      #pragma unroll
      for (int j = 0; j < 4; j++) {
        int row = j + 8 * q + 4 * h;
        int x = X0 + row;
        int accv = acc0[q * 4 + j] + acc1[q * 4 + j];
        float yv = fmaf(scl, (float)accv, bias);
        int idx = (int)fminf(fmaxf(rintf(yv * inv3), 0.0f), 127.0f);
        if (x < 254)
          a2p[((size_t)(n * 258 + (y + 2)) * 258 + (x + 2)) * 32 + oc] =
              lut[idx];
      }
    }
  }
}

// ---------------------------------------------------------------------------
// conv3 + quant3 + maxpool2x2 + pool_quant via MFMA 32x32x32.
// 2-phase LDS-staged: block stages 8 rows x 68 cols x 32 ch of a2p (17.4 KB)
// + B (25.6 KB, once) into LDS; computes a ty-PAIR of pooled rows per phase
// with tap-major schedule: one B ds_read feeds both ty MFMAs; A rows cached
// in a rolling 4-slot register window (each LDS row read once per lane).
// 4 phases per block (Yp = 4*Yq..4*Yq+3). Max-first pooling + LUT chain.
// ---------------------------------------------------------------------------
__global__ __launch_bounds__(256, 3) void k_conv3pool_mfma(
    const signed char* __restrict__ a2p, const int* __restrict__ qw3B,
    const float* __restrict__ b3, const float* __restrict__ scales,
    const float* __restrict__ wscale, signed char* __restrict__ a3p)
{
  __shared__ __align__(16) signed char ash[8 * 2176];  // [8 rows][68 cols][32 ch]
  __shared__ int bsh[6400];                            // [25 taps][64 lanes][4]
  __shared__ signed char lut56[128];
  __shared__ signed char lut67[128];

  const int tid = threadIdx.x;
  const int lane = tid & 63;
  const int w = tid >> 6;

  const int bid = blockIdx.x;
  const int swz = (bid & 7) * 256 + (bid >> 3);  // XCD-chunked (2048%8==0)
  const int n  = swz >> 6;
  const int Xg = (swz >> 4) & 3;
  const int Yq = swz & 15;
  const int c0 = 64 * Xg;

  const int oc = lane & 31, h = lane >> 5;
  const int rr = lane & 31;
  const int pp = rr >> 2, dy = (rr >> 1) & 1, dx = rr & 1;
  const int xl = 8 * w + pp;                       // local pooled px 0..31
  const int colb = (2 * xl + dx) * 32 + h * 16;    // col-byte base (kx adds 32)
  const int X0w = 32 * Xg + 8 * w;

  const float inv5 = 1.0f / scales[5];
  const float scl = scales[4] * wscale[2];
  const float bias = b3[oc];

  // stage B + LUTs once
  {
    const int4* srcB = (const int4*)qw3B;
    int4* dstB = (int4*)bsh;
    for (int i = tid; i < 1600; i += 256) dstB[i] = srcB[i];
    if (tid < 128) {
      float s5 = scales[5], s6 = scales[6];
      float inv6 = 1.0f / s6, inv7 = 1.0f / scales[7];
      lut56[tid] = (signed char)(int)fminf(rintf(((float)tid * s5) * inv6), 127.0f);
      lut67[tid] = (signed char)(int)fminf(rintf(((float)tid * s6) * inv7), 127.0f);
    }
  }

  #pragma unroll 1
  for (int it = 0; it < 4; ++it) {
    const int Yp = 4 * Yq + it;
    const int r0 = 4 * Yp;

    __syncthreads();          // prev compute done (and B staged, it==0)
    // stage A: 8 rows x 136 16B-chunks = 1088 chunks
    for (int ci = tid; ci < 1088; ci += 256) {
      int row = ci / 136;
      int cr = ci - row * 136;
      int col = cr >> 1, half = cr & 1;
      int gr = min(r0 + row, 257);
      int gc = min(c0 + col, 257);
      const int4* srcA = (const int4*)(a2p +
          (((size_t)n * 258 + gr) * 258 + gc) * 32 + half * 16);
      *(int4*)(&ash[row * 2176 + cr * 16]) = *srcA;
    }
    __syncthreads();

    // tap-major ty-pair compute with rolling A-row window
    i32x16 acc0, acc1;
    #pragma unroll
    for (int z = 0; z < 16; z++) { acc0[z] = 0; acc1[z] = 0; }

    i32x4 F0[5], F1[5], F2[5], F3[5];

#define LOAD_ROW(F, J)                                                   \
    {                                                                    \
      const signed char* rbase = &ash[(dy + (J)) * 2176 + colb];         \
      _Pragma("unroll")                                                  \
      for (int kx = 0; kx < 5; kx++)                                     \
        F[kx] = *(const i32x4*)(rbase + kx * 32);                        \
    }
#define STEP(KY, RA, RB)                                                 \
    {                                                                    \
      _Pragma("unroll")                                                  \
      for (int kx = 0; kx < 5; kx++) {                                   \
        i32x4 bfrag = *(const i32x4*)&bsh[(((KY) * 5 + kx) * 64 + lane) * 4]; \
        acc0 = __builtin_amdgcn_mfma_i32_32x32x32_i8(RA[kx], bfrag, acc0, 0, 0, 0); \
        acc1 = __builtin_amdgcn_mfma_i32_32x32x32_i8(RB[kx], bfrag, acc1, 0, 0, 0); \
      }                                                                  \
    }

    LOAD_ROW(F0, 0) LOAD_ROW(F1, 1) LOAD_ROW(F2, 2)
    LOAD_ROW(F3, 3) STEP(0, F0, F2)
    LOAD_ROW(F0, 4) STEP(1, F1, F3)
    LOAD_ROW(F1, 5) STEP(2, F2, F0)
    LOAD_ROW(F2, 6) STEP(3, F3, F1)
    STEP(4, F0, F2)
#undef LOAD_ROW
#undef STEP

    // epilogue: pooled block b = 2q+h per reg-quad q; max-first + LUT chain
    #pragma unroll
    for (int ty = 0; ty < 2; ty++) {
      int Y = 2 * Yp + ty;
      #pragma unroll
      for (int q = 0; q < 4; q++) {
        int b = 2 * q + h;
        int X = X0w + b;
        int a0, a1v, a2, a3;
        if (ty == 0) {
          a0 = acc0[q * 4 + 0]; a1v = acc0[q * 4 + 1];
          a2 = acc0[q * 4 + 2]; a3 = acc0[q * 4 + 3];
        } else {
          a0 = acc1[q * 4 + 0]; a1v = acc1[q * 4 + 1];
          a2 = acc1[q * 4 + 2]; a3 = acc1[q * 4 + 3];
        }
        int am = max(max(a0, a1v), max(a2, a3));
        float yv = fmaf(scl, (float)am, bias);
        int r1 = (int)fminf(fmaxf(rintf(yv * inv5), 0.0f), 127.0f);
        int r2 = lut56[r1];
        int r3 = lut67[r2];
        if (X < 127 && Y < 127)
          a3p[((size_t)(n * 127 + Y) * 127 + X) * 32 + oc] = (signed char)r3;
      }
    }
  }
}

// ---------------------------------------------------------------------------
// conv4 via MFMA 16x16x64 (unchanged from R6, proven).
// ---------------------------------------------------------------------------
__global__ __launch_bounds__(256) void k_conv4_mfma(
    const signed char* __restrict__ a3p, const int* __restrict__ qw4B,
    const float* __restrict__ b4, const float* __restrict__ scales,
    const float* __restrict__ wscale, signed char* __restrict__ a4b)
{
  __shared__ signed char lut[128];
  if (threadIdx.x < 128) {
    float s8 = scales[8], inv9 = 1.0f / scales[9];
    lut[threadIdx.x] =
        (signed char)(int)fminf(rintf(((float)threadIdx.x * s8) * inv9), 127.0f);
  }
  __syncthreads();

  const int lane = threadIdx.x & 63;
  const int bid = blockIdx.x;
  const int swz = (bid & 7) * 256 + (bid >> 3);
  const int gw = swz * 4 + (threadIdx.x >> 6);

  i32x4 bw[5];
  #pragma unroll
  for (int t = 0; t < 5; t++)
    bw[t] = *(const i32x4*)(qw4B + (t * 64 + lane) * 4);

  const int chunk = lane >> 4;
  int offB[5];
  #pragma unroll
  for (int mf = 0; mf < 5; mf++) {
    int tp = 2 * mf + (chunk >> 1);
    if (tp > 8) tp = 8;
    int ky = tp / 3, kx = tp % 3;
    offB[mf] = (ky * 127 + kx) * 32 + (chunk & 1) * 16;
  }

  const float inv8 = 1.0f / scales[8];
  const float scl = scales[7] * wscale[3];
  const int oc = lane & 15;
  const float bias = b4[oc];
  const int arow = lane & 15;

  const int TILES = 32 * 125 * 8;
  #pragma unroll 1
  for (int t4 = 0; t4 < 4; t4++) {
    int tile = gw * 4 + t4;
    if (tile >= TILES) break;
    int n = tile / 1000;
    int r = tile % 1000;
    int y = r >> 3, X0 = (r & 7) * 16;

    const signed char* base =
        a3p + ((size_t)n * 16129 + (size_t)y * 127 + (X0 + arow)) * 32;

    i32x4 Af[5];
    #pragma unroll
    for (int mf = 0; mf < 5; mf++)
      Af[mf] = *(const i32x4*)(base + offB[mf]);

    i32x4 acc;
    acc[0] = 0; acc[1] = 0; acc[2] = 0; acc[3] = 0;
    #pragma unroll
    for (int mf = 0; mf < 5; mf++)
      acc = __builtin_amdgcn_mfma_i32_16x16x64_i8(Af[mf], bw[mf], acc, 0, 0, 0);

    #pragma unroll
    for (int j = 0; j < 4; j++) {
      int x = X0 + chunk * 4 + j;
      float yv = fmaf(scl, (float)acc[j], bias);
      int idx = (int)fminf(fmaxf(rintf(yv * inv8), 0.0f), 127.0f);
      if (x < 125)
        a4b[((size_t)(n * 125 + y) * 125 + x) * 16 + oc] = lut[idx];
    }
  }
}

// ---------------------------------------------------------------------------
// GAP stage + FC (unchanged from R6).
// ---------------------------------------------------------------------------
__global__ __launch_bounds__(256) void k_gap_stage(
    const int* __restrict__ a4, int* __restrict__ gap_acc)
{
  int img = blockIdx.x >> 4, chunk = blockIdx.x & 15;
  int tid = threadIdx.x, lane = tid & 63;
  int p0 = chunk * 977, p1 = min(p0 + 977, 15625);

  int loc[16];
  #pragma unroll
  for (int i = 0; i < 16; i++) loc[i] = 0;
  for (int p = p0 + tid; p < p1; p += 256) {
    int4 v = *(const int4*)(a4 + (img * 15625 + p) * 4);
    int w[4] = {v.x, v.y, v.z, v.w};
    #pragma unroll
    for (int wi = 0; wi < 4; wi++)
      #pragma unroll
      for (int j = 0; j < 4; j++)
        loc[wi * 4 + j] += (int)(signed char)(w[wi] >> (8 * j));
  }
  #pragma unroll
  for (int c = 0; c < 16; c++) {
    #pragma unroll
    for (int off = 32; off > 0; off >>= 1)
      loc[c] += __shfl_down(loc[c], off);
  }
  if (lane == 0) {
    #pragma unroll
    for (int c = 0; c < 16; c++) atomicAdd(&gap_acc[img * 16 + c], loc[c]);
  }
}

__global__ __launch_bounds__(64) void k_fc(
    const int* __restrict__ gap_acc, const int* __restrict__ qwc,
    const float* __restrict__ bc, const float* __restrict__ scales,
    const float* __restrict__ wscale, float* __restrict__ out)
{
  __shared__ int sq[16];
  int n = blockIdx.x, tid = threadIdx.x;
  if (tid < 16) {
    int s = gap_acc[n * 16 + tid];
    float v = scales[9] * (float)s / 15625.0f;
    float r = fminf(fmaxf(rintf(v / scales[10]), -128.0f), 127.0f);
    sq[tid] = (int)r;
  }
  __syncthreads();
  if (tid < 10) {
    int acc = 0;
    #pragma unroll
    for (int k4 = 0; k4 < 4; k4++) {
      int wv = qwc[tid * 4 + k4];
      #pragma unroll
      for (int j = 0; j < 4; j++)
        acc += sq[k4 * 4 + j] * (int)(signed char)(wv >> (8 * j));
    }
    out[n * 10 + tid] = fmaf(scales[10] * wscale[4], (float)acc, bc[tid]);
  }
}

// ---------------------------------------------------------------------------
// Workspace layout (bytes), peak 101,259,264 (proven):
//   0         wscale (5 floats)
//   64        qw1   144 ints
//   1024      qw2B  1536 ints
//   8192      qw3B  6400 ints
//   36864     qw4B  1280 ints
//   43008     qwc   40 ints
//   49152     gap_acc 512 ints (2 KB, memset each launch)
//   65536     a2p [32][258][258][32] i8 = 68,161,536 -> ends 68,227,072
//             aliased by q0 (2 MB, dead pre-border-zero) and a4 (8 MB, conv4+)
//   68227072  a1 [32][254][254][16] i8 = 33,032,192 -> ends 101,259,264
//             aliased by a3p (16,516,096; a1 dead by conv3)
// ---------------------------------------------------------------------------
extern "C" void kernel_launch(void* const* d_in, const int* in_sizes, int n_in,
                              void* d_out, int out_size, void* d_ws, size_t ws_size,
                              hipStream_t stream) {
  const float* x  = (const float*)d_in[0];
  const float* w1 = (const float*)d_in[1];
  const float* b1 = (const float*)d_in[2];
  const float* w2 = (const float*)d_in[3];
  const float* b2 = (const float*)d_in[4];
  const float* w3 = (const float*)d_in[5];
  const float* b3 = (const float*)d_in[6];
  const float* w4 = (const float*)d_in[7];
  const float* b4 = (const float*)d_in[8];
  const float* wc = (const float*)d_in[9];
  const float* bc = (const float*)d_in[10];
  const float* sc = (const float*)d_in[11];

  char* ws = (char*)d_ws;
  float* wscale = (float*)(ws + 0);
  int* qw1  = (int*)(ws + 64);
  int* qw2B = (int*)(ws + 1024);
  int* qw3B = (int*)(ws + 8192);
  int* qw4B = (int*)(ws + 36864);
  int* qwc  = (int*)(ws + 43008);
  int* gap_acc = (int*)(ws + 49152);
  signed char* a2p = (signed char*)(ws + 65536);
  int*  q0  = (int*)(ws + 65536);                    // alias (dead pre-border)
  int*  a4  = (int*)(ws + 65536);                    // alias (a2p dead by conv4)
  int*  a1  = (int*)(ws + 68227072);
  signed char* a3p = (signed char*)(ws + 68227072);  // alias (a1 dead by conv3)
  float* out = (float*)d_out;

  hipMemsetAsync(gap_acc, 0, 2048, stream);
  k_quant_weights<<<5, 256, 0, stream>>>(w1, w2, w3, w4, wc, wscale,
                                         qw1, qw2B, qw3B, qw4B, qwc);
  k_quant_input<<<2048, 256, 0, stream>>>(x, sc, q0);
  k_conv1<<<8065, 256, 0, stream>>>((const signed char*)q0, qw1, b1, sc, wscale, a1);
  k_zero_border<<<256, 256, 0, stream>>>((int*)a2p);
  k_conv2_mfma<<<2048, 256, 0, stream>>>(a1, qw2B, b2, sc, wscale, a2p);
  k_conv3pool_mfma<<<2048, 256, 0, stream>>>(a2p, qw3B, b3, sc, wscale, a3p);
  k_conv4_mfma<<<2048, 256, 0, stream>>>(a3p, qw4B, b4, sc, wscale,
                                         (signed char*)a4);
  k_gap_stage<<<512, 256, 0, stream>>>(a4, gap_acc);
  k_fc<<<32, 64, 0, stream>>>(gap_acc, qwc, bc, sc, wscale, out);
}

// Round 9
// 276.108 us; speedup vs baseline: 3.0353x; 1.0108x over previous
//
#include <hip/hip_runtime.h>
#include <math.h>

// ---------------------------------------------------------------------------
// Quantized CNN forward (PaddingNet). conv2/conv3/conv4 on the i8 MFMA pipe;
// conv1 IMAD. Integer conv math exact; quant epilogues via 128-entry LUTs.
// conv2: single-phase LDS-staged slab (10x68 px), halo zero-filled.
// conv3: LDS-staged 2-phase, ty-pair, rolling A-row register window.
// ---------------------------------------------------------------------------

typedef int i32x4  __attribute__((ext_vector_type(4)));
typedef int i32x16 __attribute__((ext_vector_type(16)));

__device__ __forceinline__ int quant_clip(float v) {
  float r = rintf(v);
  r = fminf(fmaxf(r, -128.0f), 127.0f);
  return (int)r;
}

__device__ __forceinline__ int pack4i8(int q0, int q1, int q2, int q3) {
  return (q0 & 255) | ((q1 & 255) << 8) | ((q2 & 255) << 16) | ((q3 & 255) << 24);
}

// ---------------------------------------------------------------------------
// Weight quantization + MFMA B-fragment packing (unchanged, proven).
// ---------------------------------------------------------------------------
__global__ __launch_bounds__(256) void k_quant_weights(
    const float* __restrict__ w1, const float* __restrict__ w2,
    const float* __restrict__ w3, const float* __restrict__ w4,
    const float* __restrict__ wc, float* __restrict__ wscale,
    int* __restrict__ qw1, int* __restrict__ qw2B, int* __restrict__ qw3B,
    int* __restrict__ qw4B, int* __restrict__ qwc)
{
  __shared__ float red[256];
  __shared__ float ssh;
  const int t = blockIdx.x, tid = threadIdx.x;
  const float* src = (t == 0) ? w1 : (t == 1) ? w2 : (t == 2) ? w3 : (t == 3) ? w4 : wc;
  const int nsrc   = (t == 0) ? 144 : (t == 1) ? 4608 : (t == 2) ? 25600 : (t == 3) ? 4608 : 160;

  float m = 0.0f;
  for (int i = tid; i < nsrc; i += 256) m = fmaxf(m, fabsf(src[i]));
  red[tid] = m;
  __syncthreads();
  for (int s = 128; s > 0; s >>= 1) {
    if (tid < s) red[tid] = fmaxf(red[tid], red[tid + s]);
    __syncthreads();
  }
  if (tid == 0) { ssh = red[0] / 127.0f; wscale[t] = ssh; }
  __syncthreads();
  const float s = ssh;

  if (t == 0) {
    for (int i = tid; i < 144; i += 256) qw1[i] = quant_clip(w1[i] / s);
  } else if (t == 1) {          // w2 [32][16][3][3] -> 6 ksteps
    for (int wi = tid; wi < 1536; wi += 256) {
      int step = wi >> 8, rem = wi & 255;
      int ln = rem >> 2, w = rem & 3;
      int oc = ln & 31, h = ln >> 5;
      int ky = step >> 1, kxp = (step & 1) * 2;
      int q[4];
      #pragma unroll
      for (int j = 0; j < 4; j++) {
        int k = h * 16 + w * 4 + j;
        int ic = k & 15, kx = kxp + (k >> 4);
        float val = (kx < 3) ? w2[((oc * 16 + ic) * 3 + ky) * 3 + kx] : 0.0f;
        q[j] = quant_clip(val / s);
      }
      qw2B[wi] = pack4i8(q[0], q[1], q[2], q[3]);
    }
  } else if (t == 2) {          // w3 [32][32][5][5] -> 25 taps
    for (int wi = tid; wi < 6400; wi += 256) {
      int tap = wi >> 8, rem = wi & 255;
      int ln = rem >> 2, w = rem & 3;
      int oc = ln & 31, h = ln >> 5;
      int ky = tap / 5, kx = tap % 5;
      int q[4];
      #pragma unroll
      for (int j = 0; j < 4; j++) {
        int ic = h * 16 + w * 4 + j;
        q[j] = quant_clip(w3[((oc * 32 + ic) * 5 + ky) * 5 + kx] / s);
      }
      qw3B[wi] = pack4i8(q[0], q[1], q[2], q[3]);
    }
  } else if (t == 3) {          // w4 [16][32][3][3] -> 5 mf of 16x16x64 B-frags
    for (int wi = tid; wi < 1280; wi += 256) {
      int mf = wi >> 8, rem = wi & 255;
      int ln = rem >> 2, w = rem & 3;
      int oc = ln & 15, chunk = ln >> 4;
      int tp = 2 * mf + (chunk >> 1);
      int half = chunk & 1;
      int q[4];
      #pragma unroll
      for (int j = 0; j < 4; j++) {
        float val = 0.0f;
        if (tp < 9) {
          int ky = tp / 3, kx = tp % 3;
          int ic = half * 16 + w * 4 + j;
          val = w4[((oc * 32 + ic) * 3 + ky) * 3 + kx];
        }
        q[j] = quant_clip(val / s);
      }
      qw4B[wi] = pack4i8(q[0], q[1], q[2], q[3]);
    }
  } else {                      // wc [10][16] -> [10][4]
    for (int wi = tid; wi < 40; wi += 256) {
      int o = wi / 4, i4 = wi % 4;
      int q[4];
      #pragma unroll
      for (int j = 0; j < 4; j++) q[j] = quant_clip(wc[o * 16 + i4 * 4 + j] / s);
      qwc[wi] = pack4i8(q[0], q[1], q[2], q[3]);
    }
  }
}

// ---------------------------------------------------------------------------
// Input fake-quant.
// ---------------------------------------------------------------------------
__global__ __launch_bounds__(256) void k_quant_input(
    const float* __restrict__ x, const float* __restrict__ scales,
    int* __restrict__ q0w)
{
  int i = blockIdx.x * 256 + threadIdx.x;
  if (i >= 524288) return;
  float inv = 1.0f / scales[0];
  float4 v = ((const float4*)x)[i];
  q0w[i] = pack4i8(quant_clip(v.x * inv), quant_clip(v.y * inv),
                   quant_clip(v.z * inv), quant_clip(v.w * inv));
}

// ---------------------------------------------------------------------------
// Zero a2p's 2-px padding ring.
// ---------------------------------------------------------------------------
__global__ __launch_bounds__(256) void k_zero_border(int* __restrict__ a2p)
{
  int i = blockIdx.x * 256 + threadIdx.x;     // 65536 threads = 32 x 2048 px
  int n = i >> 11, p = i & 2047;
  int row, col;
  if (p < 1032) {
    int rb = p / 258;
    row = (rb < 2) ? rb : 254 + rb;
    col = p % 258;
  } else {
    int q = p - 1032;
    int cb = q & 3;
    col = (cb < 2) ? cb : 254 + cb;
    row = 2 + (q >> 2);
  }
  int4* dst = (int4*)(a2p + (((size_t)n * 258 + row) * 258 + col) * 8);
  dst[0] = make_int4(0, 0, 0, 0);
  dst[1] = make_int4(0, 0, 0, 0);
}

// ---------------------------------------------------------------------------
// conv1: 1->16ch, 3x3, pad0 (IMAD) + LUT epilogue.
// ---------------------------------------------------------------------------
__global__ __launch_bounds__(256) void k_conv1(
    const signed char* __restrict__ q0, const int* __restrict__ qw1,
    const float* __restrict__ b1, const float* __restrict__ scales,
    const float* __restrict__ wscale, int* __restrict__ a1)
{
  __shared__ int wsh[144];
  __shared__ signed char lut[128];
  if (threadIdx.x < 144) wsh[threadIdx.x] = qw1[threadIdx.x];
  if (threadIdx.x < 128) {
    float s1 = scales[1], inv2 = 1.0f / scales[2];
    lut[threadIdx.x] =
        (signed char)(int)fminf(rintf(((float)threadIdx.x * s1) * inv2), 127.0f);
  }
  __syncthreads();

  int pix = blockIdx.x * 256 + threadIdx.x;
  const int TOT = 32 * 254 * 254;
  if (pix >= TOT) return;
  int n = pix / (254 * 254), r = pix % (254 * 254);
  int oy = r / 254, ox = r % 254;

  int av[9];
  const signed char* base = q0 + (n * 256 + oy) * 256 + ox;
  #pragma unroll
  for (int ky = 0; ky < 3; ky++)
    #pragma unroll
    for (int kx = 0; kx < 3; kx++)
      av[ky * 3 + kx] = (int)base[ky * 256 + kx];

  float inv1 = 1.0f / scales[1];
  float scl = scales[0] * wscale[0];
  int outw[4];
  #pragma unroll
  for (int g = 0; g < 4; g++) {
    int q[4];
    #pragma unroll
    for (int j = 0; j < 4; j++) {
      int oc = g * 4 + j;
      int acc = 0;
      #pragma unroll
      for (int k = 0; k < 9; k++) acc += av[k] * wsh[oc * 9 + k];
      float y = fmaf(scl, (float)acc, b1[oc]);
      int idx = (int)fminf(fmaxf(rintf(y * inv1), 0.0f), 127.0f);
      q[j] = lut[idx];
    }
    outw[g] = pack4i8(q[0], q[1], q[2], q[3]);
  }
  *(int4*)(a1 + pix * 4) = make_int4(outw[0], outw[1], outw[2], outw[3]);
}

// ---------------------------------------------------------------------------
// conv2 via MFMA 32x32x32, LDS-staged. Block = 8 output rows x 64 cols.
// Stages [10 rows][68 px][16B] slab (10.9 KB) with zero-filled halo; each
// a1 row fetched from global ONCE (45 MB total vs 402 MB im2col re-reads).
// 4 waves x 4 slots (rows {w, w+4} x col-halves). B-frags in VGPRs.
// ---------------------------------------------------------------------------
__global__ __launch_bounds__(256) void k_conv2_lds(
    const int* __restrict__ a1, const int* __restrict__ qw2B,
    const float* __restrict__ b2, const float* __restrict__ scales,
    const float* __restrict__ wscale, signed char* __restrict__ a2p)
{
  __shared__ __align__(16) int ash2[10 * 68 * 4];   // [10 rows][68 px][4 ints]
  __shared__ signed char lut[128];

  const int tid = threadIdx.x;
  if (tid < 128) {
    float s3 = scales[3], inv4 = 1.0f / scales[4];
    lut[tid] = (signed char)(int)fminf(rintf(((float)tid * s3) * inv4), 127.0f);
  }

  const int lane = tid & 63;
  const int w = tid >> 6;
  const int bid = blockIdx.x;
  const int swz = (bid & 7) * 512 + (bid >> 3);     // XCD-chunked (4096%8==0)
  const int n   = swz >> 7;
  const int rem = swz & 127;
  const int rg = rem >> 2, cg = rem & 3;
  const int r0 = rg * 8, c0 = cg * 64;

  // stage slab: rows r0-1..r0+8, cols c0-1..c0+66 (zero-filled OOB)
  for (int ci = tid; ci < 680; ci += 256) {
    int row = ci / 68, col = ci - row * 68;
    int gr = r0 - 1 + row, gc = c0 - 1 + col;
    i32x4 v; v[0] = 0; v[1] = 0; v[2] = 0; v[3] = 0;
    if ((unsigned)gr < 254u && (unsigned)gc < 254u)
      v = *(const i32x4*)(a1 + ((n * 254 + gr) * 254 + gc) * 4);
    *(i32x4*)&ash2[ci * 4] = v;
  }

  i32x4 bw[6];
  #pragma unroll
  for (int t = 0; t < 6; t++)
    bw[t] = *(const i32x4*)(qw2B + (t * 64 + lane) * 4);

  const float inv3 = 1.0f / scales[3];
  const float scl = scales[2] * wscale[1];
  const int oc = lane & 31, h = lane >> 5, rr = lane & 31;
  const float bias = b2[oc];

  __syncthreads();

  #pragma unroll 1
  for (int k = 0; k < 4; k++) {
    int s = k * 4 + w;
    int yl = s & 7, half = s >> 3;

    i32x4 Af[6];
    #pragma unroll
    for (int ky = 0; ky < 3; ky++) {
      #pragma unroll
      for (int kp = 0; kp < 2; kp++) {
        int srow = yl + ky;
        int scol = half * 32 + rr + kp * 2 + h;   // 0..66
        Af[ky * 2 + kp] = *(const i32x4*)&ash2[(srow * 68 + scol) * 4];
      }
    }

    i32x16 acc0, acc1;
    #pragma unroll
    for (int z = 0; z < 16; z++) { acc0[z] = 0; acc1[z] = 0; }
    #pragma unroll
    for (int ky = 0; ky < 3; ky++) {
      acc0 = __builtin_amdgcn_mfma_i32_32x32x32_i8(Af[ky * 2 + 0], bw[ky * 2 + 0], acc0, 0, 0, 0);
      acc1 = __builtin_amdgcn_mfma_i32_32x32x32_i8(Af[ky * 2 + 1], bw[ky * 2 + 1], acc1, 0, 0, 0);
    }

    // C layout: col=lane&31 (oc), row=(reg&3)+8*(reg>>2)+4*(lane>>5) (px)
    int y = r0 + yl;
    #pragma unroll
    for (int q = 0; q < 4; q++) {
      #pragma unroll
      for (int j = 0; j < 4; j++) {
        int rowp = j + 8 * q + 4 * h;
        int x = c0 + half * 32 + rowp;
        int accv = acc0[q * 4 + j] + acc1[q * 4 + j];
        float yv = fmaf(scl, (float)accv, bias);
        int idx = (int)fminf(fmaxf(rintf(yv * inv3), 0.0f), 127.0f);
        if (x < 254 && y < 254)
          a2p[((size_t)(n * 258 + (y + 2)) * 258 + (x + 2)) * 32 + oc] =
              lut[idx];
      }
    }
  }
}

// ---------------------------------------------------------------------------
// conv3 + quant3 + maxpool2x2 + pool_quant via MFMA 32x32x32 (unchanged R7).
// ---------------------------------------------------------------------------
__global__ __launch_bounds__(256, 3) void k_conv3pool_mfma(
    const signed char* __restrict__ a2p, const int* __restrict__ qw3B,
    const float* __restrict__ b3, const float* __restrict__ scales,
    const float* __restrict__ wscale, signed char* __restrict__ a3p)
{
  __shared__ __align__(16) signed char ash[8 * 2176];  // [8 rows][68 cols][32 ch]
  __shared__ int bsh[6400];                            // [25 taps][64 lanes][4]
  __shared__ signed char lut56[128];
  __shared__ signed char lut67[128];

  const int tid = threadIdx.x;
  const int lane = tid & 63;
  const int w = tid >> 6;

  const int bid = blockIdx.x;
  const int swz = (bid & 7) * 256 + (bid >> 3);  // XCD-chunked (2048%8==0)
  const int n  = swz >> 6;
  const int Xg = (swz >> 4) & 3;
  const int Yq = swz & 15;
  const int c0 = 64 * Xg;

  const int oc = lane & 31, h = lane >> 5;
  const int rr = lane & 31;
  const int pp = rr >> 2, dy = (rr >> 1) & 1, dx = rr & 1;
  const int xl = 8 * w + pp;
  const int colb = (2 * xl + dx) * 32 + h * 16;
  const int X0w = 32 * Xg + 8 * w;

  const float inv5 = 1.0f / scales[5];
  const float scl = scales[4] * wscale[2];
  const float bias = b3[oc];

  {
    const int4* srcB = (const int4*)qw3B;
    int4* dstB = (int4*)bsh;
    for (int i = tid; i < 1600; i += 256) dstB[i] = srcB[i];
    if (tid < 128) {
      float s5 = scales[5], s6 = scales[6];
      float inv6 = 1.0f / s6, inv7 = 1.0f / scales[7];
      lut56[tid] = (signed char)(int)fminf(rintf(((float)tid * s5) * inv6), 127.0f);
      lut67[tid] = (signed char)(int)fminf(rintf(((float)tid * s6) * inv7), 127.0f);
    }
  }

  #pragma unroll 1
  for (int it = 0; it < 4; ++it) {
    const int Yp = 4 * Yq + it;
    const int r0 = 4 * Yp;

    __syncthreads();
    for (int ci = tid; ci < 1088; ci += 256) {
      int row = ci / 136;
      int cr = ci - row * 136;
      int col = cr >> 1, half = cr & 1;
      int gr = min(r0 + row, 257);
      int gc = min(c0 + col, 257);
      const int4* srcA = (const int4*)(a2p +
          (((size_t)n * 258 + gr) * 258 + gc) * 32 + half * 16);
      *(int4*)(&ash[row * 2176 + cr * 16]) = *srcA;
    }
    __syncthreads();

    i32x16 acc0, acc1;
    #pragma unroll
    for (int z = 0; z < 16; z++) { acc0[z] = 0; acc1[z] = 0; }

    i32x4 F0[5], F1[5], F2[5], F3[5];

#define LOAD_ROW(F, J)                                                   \
    {                                                                    \
      const signed char* rbase = &ash[(dy + (J)) * 2176 + colb];         \
      _Pragma("unroll")                                                  \
      for (int kx = 0; kx < 5; kx++)                                     \
        F[kx] = *(const i32x4*)(rbase + kx * 32);                        \
    }
#define STEP(KY, RA, RB)                                                 \
    {                                                                    \
      _Pragma("unroll")                                                  \
      for (int kx = 0; kx < 5; kx++) {                                   \
        i32x4 bfrag = *(const i32x4*)&bsh[(((KY) * 5 + kx) * 64 + lane) * 4]; \
        acc0 = __builtin_amdgcn_mfma_i32_32x32x32_i8(RA[kx], bfrag, acc0, 0, 0, 0); \
        acc1 = __builtin_amdgcn_mfma_i32_32x32x32_i8(RB[kx], bfrag, acc1, 0, 0, 0); \
      }                                                                  \
    }

    LOAD_ROW(F0, 0) LOAD_ROW(F1, 1) LOAD_ROW(F2, 2)
    LOAD_ROW(F3, 3) STEP(0, F0, F2)
    LOAD_ROW(F0, 4) STEP(1, F1, F3)
    LOAD_ROW(F1, 5) STEP(2, F2, F0)
    LOAD_ROW(F2, 6) STEP(3, F3, F1)
    STEP(4, F0, F2)
#undef LOAD_ROW
#undef STEP

    #pragma unroll
    for (int ty = 0; ty < 2; ty++) {
      int Y = 2 * Yp + ty;
      #pragma unroll
      for (int q = 0; q < 4; q++) {
        int b = 2 * q + h;
        int X = X0w + b;
        int a0, a1v, a2, a3;
        if (ty == 0) {
          a0 = acc0[q * 4 + 0]; a1v = acc0[q * 4 + 1];
          a2 = acc0[q * 4 + 2]; a3 = acc0[q * 4 + 3];
        } else {
          a0 = acc1[q * 4 + 0]; a1v = acc1[q * 4 + 1];
          a2 = acc1[q * 4 + 2]; a3 = acc1[q * 4 + 3];
        }
        int am = max(max(a0, a1v), max(a2, a3));
        float yv = fmaf(scl, (float)am, bias);
        int r1 = (int)fminf(fmaxf(rintf(yv * inv5), 0.0f), 127.0f);
        int r2 = lut56[r1];
        int r3 = lut67[r2];
        if (X < 127 && Y < 127)
          a3p[((size_t)(n * 127 + Y) * 127 + X) * 32 + oc] = (signed char)r3;
      }
    }
  }
}

// ---------------------------------------------------------------------------
// conv4 via MFMA 16x16x64 (unchanged, proven).
// ---------------------------------------------------------------------------
__global__ __launch_bounds__(256) void k_conv4_mfma(
    const signed char* __restrict__ a3p, const int* __restrict__ qw4B,
    const float* __restrict__ b4, const float* __restrict__ scales,
    const float* __restrict__ wscale, signed char* __restrict__ a4b)
{
  __shared__ signed char lut[128];
  if (threadIdx.x < 128) {
    float s8 = scales[8], inv9 = 1.0f / scales[9];
    lut[threadIdx.x] =
        (signed char)(int)fminf(rintf(((float)threadIdx.x * s8) * inv9), 127.0f);
  }
  __syncthreads();

  const int lane = threadIdx.x & 63;
  const int bid = blockIdx.x;
  const int swz = (bid & 7) * 256 + (bid >> 3);
  const int gw = swz * 4 + (threadIdx.x >> 6);

  i32x4 bw[5];
  #pragma unroll
  for (int t = 0; t < 5; t++)
    bw[t] = *(const i32x4*)(qw4B + (t * 64 + lane) * 4);

  const int chunk = lane >> 4;
  int offB[5];
  #pragma unroll
  for (int mf = 0; mf < 5; mf++) {
    int tp = 2 * mf + (chunk >> 1);
    if (tp > 8) tp = 8;
    int ky = tp / 3, kx = tp % 3;
    offB[mf] = (ky * 127 + kx) * 32 + (chunk & 1) * 16;
  }

  const float inv8 = 1.0f / scales[8];
  const float scl = scales[7] * wscale[3];
  const int oc = lane & 15;
  const float bias = b4[oc];
  const int arow = lane & 15;

  const int TILES = 32 * 125 * 8;
  #pragma unroll 1
  for (int t4 = 0; t4 < 4; t4++) {
    int tile = gw * 4 + t4;
    if (tile >= TILES) break;
    int n = tile / 1000;
    int r = tile % 1000;
    int y = r >> 3, X0 = (r & 7) * 16;

    const signed char* base =
        a3p + ((size_t)n * 16129 + (size_t)y * 127 + (X0 + arow)) * 32;

    i32x4 Af[5];
    #pragma unroll
    for (int mf = 0; mf < 5; mf++)
      Af[mf] = *(const i32x4*)(base + offB[mf]);

    i32x4 acc;
    acc[0] = 0; acc[1] = 0; acc[2] = 0; acc[3] = 0;
    #pragma unroll
    for (int mf = 0; mf < 5; mf++)
      acc = __builtin_amdgcn_mfma_i32_16x16x64_i8(Af[mf], bw[mf], acc, 0, 0, 0);

    #pragma unroll
    for (int j = 0; j < 4; j++) {
      int x = X0 + chunk * 4 + j;
      float yv = fmaf(scl, (float)acc[j], bias);
      int idx = (int)fminf(fmaxf(rintf(yv * inv8), 0.0f), 127.0f);
      if (x < 125)
        a4b[((size_t)(n * 125 + y) * 125 + x) * 16 + oc] = lut[idx];
    }
  }
}

// ---------------------------------------------------------------------------
// GAP stage + FC (unchanged).
// ---------------------------------------------------------------------------
__global__ __launch_bounds__(256) void k_gap_stage(
    const int* __restrict__ a4, int* __restrict__ gap_acc)
{
  int img = blockIdx.x >> 4, chunk = blockIdx.x & 15;
  int tid = threadIdx.x, lane = tid & 63;
  int p0 = chunk * 977, p1 = min(p0 + 977, 15625);

  int loc[16];
  #pragma unroll
  for (int i = 0; i < 16; i++) loc[i] = 0;
  for (int p = p0 + tid; p < p1; p += 256) {
    int4 v = *(const int4*)(a4 + (img * 15625 + p) * 4);
    int w[4] = {v.x, v.y, v.z, v.w};
    #pragma unroll
    for (int wi = 0; wi < 4; wi++)
      #pragma unroll
      for (int j = 0; j < 4; j++)
        loc[wi * 4 + j] += (int)(signed char)(w[wi] >> (8 * j));
  }
  #pragma unroll
  for (int c = 0; c < 16; c++) {
    #pragma unroll
    for (int off = 32; off > 0; off >>= 1)
      loc[c] += __shfl_down(loc[c], off);
  }
  if (lane == 0) {
    #pragma unroll
    for (int c = 0; c < 16; c++) atomicAdd(&gap_acc[img * 16 + c], loc[c]);
  }
}

__global__ __launch_bounds__(64) void k_fc(
    const int* __restrict__ gap_acc, const int* __restrict__ qwc,
    const float* __restrict__ bc, const float* __restrict__ scales,
    const float* __restrict__ wscale, float* __restrict__ out)
{
  __shared__ int sq[16];
  int n = blockIdx.x, tid = threadIdx.x;
  if (tid < 16) {
    int s = gap_acc[n * 16 + tid];
    float v = scales[9] * (float)s / 15625.0f;
    float r = fminf(fmaxf(rintf(v / scales[10]), -128.0f), 127.0f);
    sq[tid] = (int)r;
  }
  __syncthreads();
  if (tid < 10) {
    int acc = 0;
    #pragma unroll
    for (int k4 = 0; k4 < 4; k4++) {
      int wv = qwc[tid * 4 + k4];
      #pragma unroll
      for (int j = 0; j < 4; j++)
        acc += sq[k4 * 4 + j] * (int)(signed char)(wv >> (8 * j));
    }
    out[n * 10 + tid] = fmaf(scales[10] * wscale[4], (float)acc, bc[tid]);
  }
}

// ---------------------------------------------------------------------------
// Workspace layout (bytes), peak 101,259,264 (proven):
//   0         wscale (5 floats)
//   64        qw1   144 ints
//   1024      qw2B  1536 ints
//   8192      qw3B  6400 ints
//   36864     qw4B  1280 ints
//   43008     qwc   40 ints
//   49152     gap_acc 512 ints (2 KB, memset each launch)
//   65536     a2p [32][258][258][32] i8 = 68,161,536 -> ends 68,227,072
//             aliased by q0 (2 MB, dead pre-border-zero) and a4 (8 MB, conv4+)
//   68227072  a1 [32][254][254][16] i8 = 33,032,192 -> ends 101,259,264
//             aliased by a3p (16,516,096; a1 dead by conv3)
// ---------------------------------------------------------------------------
extern "C" void kernel_launch(void* const* d_in, const int* in_sizes, int n_in,
                              void* d_out, int out_size, void* d_ws, size_t ws_size,
                              hipStream_t stream) {
  const float* x  = (const float*)d_in[0];
  const float* w1 = (const float*)d_in[1];
  const float* b1 = (const float*)d_in[2];
  const float* w2 = (const float*)d_in[3];
  const float* b2 = (const float*)d_in[4];
  const float* w3 = (const float*)d_in[5];
  const float* b3 = (const float*)d_in[6];
  const float* w4 = (const float*)d_in[7];
  const float* b4 = (const float*)d_in[8];
  const float* wc = (const float*)d_in[9];
  const float* bc = (const float*)d_in[10];
  const float* sc = (const float*)d_in[11];

  char* ws = (char*)d_ws;
  float* wscale = (float*)(ws + 0);
  int* qw1  = (int*)(ws + 64);
  int* qw2B = (int*)(ws + 1024);
  int* qw3B = (int*)(ws + 8192);
  int* qw4B = (int*)(ws + 36864);
  int* qwc  = (int*)(ws + 43008);
  int* gap_acc = (int*)(ws + 49152);
  signed char* a2p = (signed char*)(ws + 65536);
  int*  q0  = (int*)(ws + 65536);                    // alias (dead pre-border)
  int*  a4  = (int*)(ws + 65536);                    // alias (a2p dead by conv4)
  int*  a1  = (int*)(ws + 68227072);
  signed char* a3p = (signed char*)(ws + 68227072);  // alias (a1 dead by conv3)
  float* out = (float*)d_out;

  hipMemsetAsync(gap_acc, 0, 2048, stream);
  k_quant_weights<<<5, 256, 0, stream>>>(w1, w2, w3, w4, wc, wscale,
                                         qw1, qw2B, qw3B, qw4B, qwc);
  k_quant_input<<<2048, 256, 0, stream>>>(x, sc, q0);
  k_conv1<<<8065, 256, 0, stream>>>((const signed char*)q0, qw1, b1, sc, wscale, a1);
  k_zero_border<<<256, 256, 0, stream>>>((int*)a2p);
  k_conv2_lds<<<4096, 256, 0, stream>>>(a1, qw2B, b2, sc, wscale, a2p);
  k_conv3pool_mfma<<<2048, 256, 0, stream>>>(a2p, qw3B, b3, sc, wscale, a3p);
  k_conv4_mfma<<<2048, 256, 0, stream>>>(a3p, qw4B, b4, sc, wscale,
                                         (signed char*)a4);
  k_gap_stage<<<512, 256, 0, stream>>>(a4, gap_acc);
  k_fc<<<32, 64, 0, stream>>>(gap_acc, qwc, bc, sc, wscale, out);
}

// Round 11
// 252.071 us; speedup vs baseline: 3.3247x; 1.0954x over previous
//
#include <hip/hip_runtime.h>
#include <math.h>

// ---------------------------------------------------------------------------
// Quantized CNN forward (PaddingNet). conv2/conv3/conv4 on the i8 MFMA pipe;
// conv1 IMAD (with fused input quant). Integer conv math exact; quant
// epilogues via 128-entry LUTs. conv4 fused with global-avg-pool.
// LDS tiles XOR-swizzled at 16B granularity (write+read) for bank spread.
// ---------------------------------------------------------------------------

typedef int i32x4  __attribute__((ext_vector_type(4)));
typedef int i32x16 __attribute__((ext_vector_type(16)));

__device__ __forceinline__ int quant_clip(float v) {
  float r = rintf(v);
  r = fminf(fmaxf(r, -128.0f), 127.0f);
  return (int)r;
}

__device__ __forceinline__ int pack4i8(int q0, int q1, int q2, int q3) {
  return (q0 & 255) | ((q1 & 255) << 8) | ((q2 & 255) << 16) | ((q3 & 255) << 24);
}

__device__ __forceinline__ int swz16(int c) {   // 16B-chunk XOR swizzle
  return c ^ ((c >> 3) & 7);
}

// ---------------------------------------------------------------------------
// Weight max-abs: 8 blocks/tensor, atomicMax on float bits (all >= 0).
// ---------------------------------------------------------------------------
__global__ __launch_bounds__(256) void k_wmax(
    const float* __restrict__ w1, const float* __restrict__ w2,
    const float* __restrict__ w3, const float* __restrict__ w4,
    const float* __restrict__ wc, unsigned int* __restrict__ wsraw)
{
  __shared__ float red[256];
  const int t = blockIdx.x >> 3, part = blockIdx.x & 7, tid = threadIdx.x;
  const float* src = (t == 0) ? w1 : (t == 1) ? w2 : (t == 2) ? w3 : (t == 3) ? w4 : wc;
  const int n4 = (t == 0) ? 36 : (t == 1) ? 1152 : (t == 2) ? 6400 : (t == 3) ? 1152 : 40;

  float m = 0.0f;
  for (int i = part * 256 + tid; i < n4; i += 2048) {
    float4 v = ((const float4*)src)[i];
    m = fmaxf(m, fmaxf(fmaxf(fabsf(v.x), fabsf(v.y)),
                       fmaxf(fabsf(v.z), fabsf(v.w))));
  }
  red[tid] = m;
  __syncthreads();
  for (int s = 128; s > 0; s >>= 1) {
    if (tid < s) red[tid] = fmaxf(red[tid], red[tid + s]);
    __syncthreads();
  }
  if (tid == 0) atomicMax(&wsraw[t], __float_as_uint(red[0]));
}

// ---------------------------------------------------------------------------
// Weight quantization + MFMA B-fragment packing (parallel, 8 blocks/tensor).
//  qw1:  [16][9] ints (conv1 IMAD)
//  qw2B: [6 ksteps][64 lanes][4 words]
//  qw3B: [25 taps][64 lanes][4 words]
//  qw4B: [5 mf][64 lanes][4 words] (16x16x64)
//  qwc:  [10][4] words
// ---------------------------------------------------------------------------
__global__ __launch_bounds__(256) void k_wpack(
    const float* __restrict__ w1, const float* __restrict__ w2,
    const float* __restrict__ w3, const float* __restrict__ w4,
    const float* __restrict__ wc, const unsigned int* __restrict__ wsraw,
    float* __restrict__ wscale,
    int* __restrict__ qw1, int* __restrict__ qw2B, int* __restrict__ qw3B,
    int* __restrict__ qw4B, int* __restrict__ qwc)
{
  const int t = blockIdx.x >> 3, part = blockIdx.x & 7, tid = threadIdx.x;
  const float s = __uint_as_float(wsraw[t]) / 127.0f;
  if (part == 0 && tid == 0) wscale[t] = s;
  const int base = part * 256 + tid;

  if (t == 0) {
    for (int i = base; i < 144; i += 2048) qw1[i] = quant_clip(w1[i] / s);
  } else if (t == 1) {          // w2 [32][16][3][3] -> 6 ksteps
    for (int wi = base; wi < 1536; wi += 2048) {
      int step = wi >> 8, rem = wi & 255;
      int ln = rem >> 2, w = rem & 3;
      int oc = ln & 31, h = ln >> 5;
      int ky = step >> 1, kxp = (step & 1) * 2;
      int q[4];
      #pragma unroll
      for (int j = 0; j < 4; j++) {
        int k = h * 16 + w * 4 + j;
        int ic = k & 15, kx = kxp + (k >> 4);
        float val = (kx < 3) ? w2[((oc * 16 + ic) * 3 + ky) * 3 + kx] : 0.0f;
        q[j] = quant_clip(val / s);
      }
      qw2B[wi] = pack4i8(q[0], q[1], q[2], q[3]);
    }
  } else if (t == 2) {          // w3 [32][32][5][5] -> 25 taps
    for (int wi = base; wi < 6400; wi += 2048) {
      int tap = wi >> 8, rem = wi & 255;
      int ln = rem >> 2, w = rem & 3;
      int oc = ln & 31, h = ln >> 5;
      int ky = tap / 5, kx = tap % 5;
      int q[4];
      #pragma unroll
      for (int j = 0; j < 4; j++) {
        int ic = h * 16 + w * 4 + j;
        q[j] = quant_clip(w3[((oc * 32 + ic) * 5 + ky) * 5 + kx] / s);
      }
      qw3B[wi] = pack4i8(q[0], q[1], q[2], q[3]);
    }
  } else if (t == 3) {          // w4 [16][32][3][3] -> 5 mf of 16x16x64 B-frags
    for (int wi = base; wi < 1280; wi += 2048) {
      int mf = wi >> 8, rem = wi & 255;
      int ln = rem >> 2, w = rem & 3;
      int oc = ln & 15, chunk = ln >> 4;
      int tp = 2 * mf + (chunk >> 1);
      int half = chunk & 1;
      int q[4];
      #pragma unroll
      for (int j = 0; j < 4; j++) {
        float val = 0.0f;
        if (tp < 9) {
          int ky = tp / 3, kx = tp % 3;
          int ic = half * 16 + w * 4 + j;
          val = w4[((oc * 32 + ic) * 3 + ky) * 3 + kx];
        }
        q[j] = quant_clip(val / s);
      }
      qw4B[wi] = pack4i8(q[0], q[1], q[2], q[3]);
    }
  } else {                      // wc [10][16] -> [10][4]
    for (int wi = base; wi < 40; wi += 2048) {
      int o = wi / 4, i4 = wi % 4;
      int q[4];
      #pragma unroll
      for (int j = 0; j < 4; j++) q[j] = quant_clip(wc[o * 16 + i4 * 4 + j] / s);
      qwc[wi] = pack4i8(q[0], q[1], q[2], q[3]);
    }
  }
}

// ---------------------------------------------------------------------------
// Zero a2p's 2-px padding ring.
// ---------------------------------------------------------------------------
__global__ __launch_bounds__(256) void k_zero_border(int* __restrict__ a2p)
{
  int i = blockIdx.x * 256 + threadIdx.x;     // 65536 threads = 32 x 2048 px
  int n = i >> 11, p = i & 2047;
  int row, col;
  if (p < 1032) {
    int rb = p / 258;
    row = (rb < 2) ? rb : 254 + rb;
    col = p % 258;
  } else {
    int q = p - 1032;
    int cb = q & 3;
    col = (cb < 2) ? cb : 254 + cb;
    row = 2 + (q >> 2);
  }
  int4* dst = (int4*)(a2p + (((size_t)n * 258 + row) * 258 + col) * 8);
  dst[0] = make_int4(0, 0, 0, 0);
  dst[1] = make_int4(0, 0, 0, 0);
}

// ---------------------------------------------------------------------------
// conv1: 1->16ch, 3x3, pad0 (IMAD), fused input fake-quant + LUT epilogue.
// Reads x (f32) directly; quantizes each tap on the fly (exact, same op).
// ---------------------------------------------------------------------------
__global__ __launch_bounds__(256) void k_conv1(
    const float* __restrict__ x, const int* __restrict__ qw1,
    const float* __restrict__ b1, const float* __restrict__ scales,
    const float* __restrict__ wscale, int* __restrict__ a1)
{
  __shared__ int wsh[144];
  __shared__ signed char lut[128];
  if (threadIdx.x < 144) wsh[threadIdx.x] = qw1[threadIdx.x];
  if (threadIdx.x < 128) {
    float s1 = scales[1], inv2 = 1.0f / scales[2];
    lut[threadIdx.x] =
        (signed char)(int)fminf(rintf(((float)threadIdx.x * s1) * inv2), 127.0f);
  }
  __syncthreads();

  int pix = blockIdx.x * 256 + threadIdx.x;
  const int TOT = 32 * 254 * 254;
  if (pix >= TOT) return;
  int n = pix / (254 * 254), r = pix % (254 * 254);
  int oy = r / 254, ox = r % 254;

  float inv0 = 1.0f / scales[0];
  int av[9];
  const float* base = x + (n * 256 + oy) * 256 + ox;
  #pragma unroll
  for (int ky = 0; ky < 3; ky++)
    #pragma unroll
    for (int kx = 0; kx < 3; kx++)
      av[ky * 3 + kx] = quant_clip(base[ky * 256 + kx] * inv0);

  float inv1 = 1.0f / scales[1];
  float scl = scales[0] * wscale[0];
  int outw[4];
  #pragma unroll
  for (int g = 0; g < 4; g++) {
    int q[4];
    #pragma unroll
    for (int j = 0; j < 4; j++) {
      int oc = g * 4 + j;
      int acc = 0;
      #pragma unroll
      for (int k = 0; k < 9; k++) acc += av[k] * wsh[oc * 9 + k];
      float y = fmaf(scl, (float)acc, b1[oc]);
      int idx = (int)fminf(fmaxf(rintf(y * inv1), 0.0f), 127.0f);
      q[j] = lut[idx];
    }
    outw[g] = pack4i8(q[0], q[1], q[2], q[3]);
  }
  *(int4*)(a1 + pix * 4) = make_int4(outw[0], outw[1], outw[2], outw[3]);
}

// ---------------------------------------------------------------------------
// conv2 via MFMA 32x32x32, LDS-staged + swizzled. Block = 8 rows x 64 cols.
// ---------------------------------------------------------------------------
__global__ __launch_bounds__(256) void k_conv2_lds(
    const int* __restrict__ a1, const int* __restrict__ qw2B,
    const float* __restrict__ b2, const float* __restrict__ scales,
    const float* __restrict__ wscale, signed char* __restrict__ a2p)
{
  __shared__ __align__(16) int ash2[10 * 68 * 4];   // [10 rows][68 swz-chunks]
  __shared__ signed char lut[128];

  const int tid = threadIdx.x;
  if (tid < 128) {
    float s3 = scales[3], inv4 = 1.0f / scales[4];
    lut[tid] = (signed char)(int)fminf(rintf(((float)tid * s3) * inv4), 127.0f);
  }

  const int lane = tid & 63;
  const int w = tid >> 6;
  const int bid = blockIdx.x;
  const int swz = (bid & 7) * 512 + (bid >> 3);     // XCD-chunked (4096%8==0)
  const int n   = swz >> 7;
  const int rem = swz & 127;
  const int rg = rem >> 2, cg = rem & 3;
  const int r0 = rg * 8, c0 = cg * 64;

  // stage slab: rows r0-1..r0+8, cols c0-1..c0+66 (zero-filled OOB), swizzled
  for (int ci = tid; ci < 680; ci += 256) {
    int row = ci / 68, col = ci - row * 68;
    int gr = r0 - 1 + row, gc = c0 - 1 + col;
    i32x4 v; v[0] = 0; v[1] = 0; v[2] = 0; v[3] = 0;
    if ((unsigned)gr < 254u && (unsigned)gc < 254u)
      v = *(const i32x4*)(a1 + ((n * 254 + gr) * 254 + gc) * 4);
    *(i32x4*)&ash2[(row * 68 + swz16(col)) * 4] = v;
  }

  i32x4 bw[6];
  #pragma unroll
  for (int t = 0; t < 6; t++)
    bw[t] = *(const i32x4*)(qw2B + (t * 64 + lane) * 4);

  const float inv3 = 1.0f / scales[3];
  const float scl = scales[2] * wscale[1];
  const int oc = lane & 31, h = lane >> 5, rr = lane & 31;
  const float bias = b2[oc];

  __syncthreads();

  #pragma unroll 1
  for (int k = 0; k < 4; k++) {
    int s = k * 4 + w;
    int yl = s & 7, half = s >> 3;

    i32x4 Af[6];
    #pragma unroll
    for (int ky = 0; ky < 3; ky++) {
      #pragma unroll
      for (int kp = 0; kp < 2; kp++) {
        int srow = yl + ky;
        int scol = half * 32 + rr + kp * 2 + h;   // 0..66
        Af[ky * 2 + kp] = *(const i32x4*)&ash2[(srow * 68 + swz16(scol)) * 4];
      }
    }

    i32x16 acc0, acc1;
    #pragma unroll
    for (int z = 0; z < 16; z++) { acc0[z] = 0; acc1[z] = 0; }
    #pragma unroll
    for (int ky = 0; ky < 3; ky++) {
      acc0 = __builtin_amdgcn_mfma_i32_32x32x32_i8(Af[ky * 2 + 0], bw[ky * 2 + 0], acc0, 0, 0, 0);
      acc1 = __builtin_amdgcn_mfma_i32_32x32x32_i8(Af[ky * 2 + 1], bw[ky * 2 + 1], acc1, 0, 0, 0);
    }

    int y = r0 + yl;
    #pragma unroll
    for (int q = 0; q < 4; q++) {
      #pragma unroll
      for (int j = 0; j < 4; j++) {
        int rowp = j + 8 * q + 4 * h;
        int x = c0 + half * 32 + rowp;
        int accv = acc0[q * 4 + j] + acc1[q * 4 + j];
        float yv = fmaf(scl, (float)accv, bias);
        int idx = (int)fminf(fmaxf(rintf(yv * inv3), 0.0f), 127.0f);
        if (x < 254 && y < 254)
          a2p[((size_t)(n * 258 + (y + 2)) * 258 + (x + 2)) * 32 + oc] =
              lut[idx];
      }
    }
  }
}

// ---------------------------------------------------------------------------
// conv3 + quant3 + maxpool2x2 + pool_quant via MFMA 32x32x32.
// LDS-staged, 16B-chunk swizzled (8-way bank conflict -> ~2-way).
// ---------------------------------------------------------------------------
__global__ __launch_bounds__(256, 3) void k_conv3pool_mfma(
    const signed char* __restrict__ a2p, const int* __restrict__ qw3B,
    const float* __restrict__ b3, const float* __restrict__ scales,
    const float* __restrict__ wscale, signed char* __restrict__ a3p)
{
  __shared__ __align__(16) signed char ash[8 * 2176];  // [8 rows][136 swz-chunks]
  __shared__ int bsh[6400];                            // [25 taps][64 lanes][4]
  __shared__ signed char lut56[128];
  __shared__ signed char lut67[128];

  const int tid = threadIdx.x;
  const int lane = tid & 63;
  const int w = tid >> 6;

  const int bid = blockIdx.x;
  const int swzb = (bid & 7) * 256 + (bid >> 3);  // XCD-chunked (2048%8==0)
  const int n  = swzb >> 6;
  const int Xg = (swzb >> 4) & 3;
  const int Yq = swzb & 15;
  const int c0 = 64 * Xg;

  const int oc = lane & 31, h = lane >> 5;
  const int rr = lane & 31;
  const int pp = rr >> 2, dy = (rr >> 1) & 1, dx = rr & 1;
  const int xl = 8 * w + pp;
  const int X0w = 32 * Xg + 8 * w;

  // per-lane swizzled chunk offsets (independent of row): c = 4xl+2dx+h+2kx
  int csw[5];
  {
    int c0l = 4 * xl + 2 * dx + h;
    #pragma unroll
    for (int kx = 0; kx < 5; kx++) csw[kx] = swz16(c0l + 2 * kx) * 16;
  }

  const float inv5 = 1.0f / scales[5];
  const float scl = scales[4] * wscale[2];
  const float bias = b3[oc];

  {
    const int4* srcB = (const int4*)qw3B;
    int4* dstB = (int4*)bsh;
    for (int i = tid; i < 1600; i += 256) dstB[i] = srcB[i];
    if (tid < 128) {
      float s5 = scales[5], s6 = scales[6];
      float inv6 = 1.0f / s6, inv7 = 1.0f / scales[7];
      lut56[tid] = (signed char)(int)fminf(rintf(((float)tid * s5) * inv6), 127.0f);
      lut67[tid] = (signed char)(int)fminf(rintf(((float)tid * s6) * inv7), 127.0f);
    }
  }

  #pragma unroll 1
  for (int it = 0; it < 4; ++it) {
    const int Yp = 4 * Yq + it;
    const int r0 = 4 * Yp;

    __syncthreads();
    for (int ci = tid; ci < 1088; ci += 256) {
      int row = ci / 136;
      int cr = ci - row * 136;
      int col = cr >> 1, half = cr & 1;
      int gr = min(r0 + row, 257);
      int gc = min(c0 + col, 257);
      const int4* srcA = (const int4*)(a2p +
          (((size_t)n * 258 + gr) * 258 + gc) * 32 + half * 16);
      *(int4*)(&ash[row * 2176 + swz16(cr) * 16]) = *srcA;
    }
    __syncthreads();

    i32x16 acc0, acc1;
    #pragma unroll
    for (int z = 0; z < 16; z++) { acc0[z] = 0; acc1[z] = 0; }

    i32x4 F0[5], F1[5], F2[5], F3[5];

#define LOAD_ROW(F, J)                                                   \
    {                                                                    \
      const signed char* rbase = &ash[(dy + (J)) * 2176];                \
      _Pragma("unroll")                                                  \
      for (int kx = 0; kx < 5; kx++)                                     \
        F[kx] = *(const i32x4*)(rbase + csw[kx]);                        \
    }
#define STEP(KY, RA, RB)                                                 \
    {                                                                    \
      _Pragma("unroll")                                                  \
      for (int kx = 0; kx < 5; kx++) {                                   \
        i32x4 bfrag = *(const i32x4*)&bsh[(((KY) * 5 + kx) * 64 + lane) * 4]; \
        acc0 = __builtin_amdgcn_mfma_i32_32x32x32_i8(RA[kx], bfrag, acc0, 0, 0, 0); \
        acc1 = __builtin_amdgcn_mfma_i32_32x32x32_i8(RB[kx], bfrag, acc1, 0, 0, 0); \
      }                                                                  \
    }

    LOAD_ROW(F0, 0) LOAD_ROW(F1, 1) LOAD_ROW(F2, 2)
    LOAD_ROW(F3, 3) STEP(0, F0, F2)
    LOAD_ROW(F0, 4) STEP(1, F1, F3)
    LOAD_ROW(F1, 5) STEP(2, F2, F0)
    LOAD_ROW(F2, 6) STEP(3, F3, F1)
    STEP(4, F0, F2)
#undef LOAD_ROW
#undef STEP

    #pragma unroll
    for (int ty = 0; ty < 2; ty++) {
      int Y = 2 * Yp + ty;
      #pragma unroll
      for (int q = 0; q < 4; q++) {
        int b = 2 * q + h;
        int X = X0w + b;
        int a0, a1v, a2, a3;
        if (ty == 0) {
          a0 = acc0[q * 4 + 0]; a1v = acc0[q * 4 + 1];
          a2 = acc0[q * 4 + 2]; a3 = acc0[q * 4 + 3];
        } else {
          a0 = acc1[q * 4 + 0]; a1v = acc1[q * 4 + 1];
          a2 = acc1[q * 4 + 2]; a3 = acc1[q * 4 + 3];
        }
        int am = max(max(a0, a1v), max(a2, a3));
        float yv = fmaf(scl, (float)am, bias);
        int r1 = (int)fminf(fmaxf(rintf(yv * inv5), 0.0f), 127.0f);
        int r2 = lut56[r1];
        int r3 = lut67[r2];
        if (X < 127 && Y < 127)
          a3p[((size_t)(n * 127 + Y) * 127 + X) * 32 + oc] = (signed char)r3;
      }
    }
  }
}

// ---------------------------------------------------------------------------
// conv4 via MFMA 16x16x64, FUSED with global-avg-pool: a4 never materialized;
// per-tile shuffle-reduce over pixels -> atomicAdd 16 channel partials.
// ---------------------------------------------------------------------------
__global__ __launch_bounds__(256) void k_conv4_gap(
    const signed char* __restrict__ a3p, const int* __restrict__ qw4B,
    const float* __restrict__ b4, const float* __restrict__ scales,
    const float* __restrict__ wscale, int* __restrict__ gap_acc)
{
  __shared__ signed char lut[128];
  if (threadIdx.x < 128) {
    float s8 = scales[8], inv9 = 1.0f / scales[9];
    lut[threadIdx.x] =
        (signed char)(int)fminf(rintf(((float)threadIdx.x * s8) * inv9), 127.0f);
  }
  __syncthreads();

  const int lane = threadIdx.x & 63;
  const int bid = blockIdx.x;
  const int swz = (bid & 7) * 256 + (bid >> 3);
  const int gw = swz * 4 + (threadIdx.x >> 6);

  i32x4 bw[5];
  #pragma unroll
  for (int t = 0; t < 5; t++)
    bw[t] = *(const i32x4*)(qw4B + (t * 64 + lane) * 4);

  const int chunk = lane >> 4;
  int offB[5];
  #pragma unroll
  for (int mf = 0; mf < 5; mf++) {
    int tp = 2 * mf + (chunk >> 1);
    if (tp > 8) tp = 8;                 // padded slot: B is zero, clamp addr
    int ky = tp / 3, kx = tp % 3;
    offB[mf] = (ky * 127 + kx) * 32 + (chunk & 1) * 16;
  }

  const float inv8 = 1.0f / scales[8];
  const float scl = scales[7] * wscale[3];
  const int oc = lane & 15;
  const float bias = b4[oc];
  const int arow = lane & 15;

  const int TILES = 32 * 125 * 8;
  #pragma unroll 1
  for (int t4 = 0; t4 < 4; t4++) {
    int tile = gw * 4 + t4;
    if (tile >= TILES) break;
    int n = tile / 1000;
    int r = tile % 1000;
    int y = r >> 3, X0 = (r & 7) * 16;

    const signed char* base =
        a3p + ((size_t)n * 16129 + (size_t)y * 127 + (X0 + arow)) * 32;

    i32x4 Af[5];
    #pragma unroll
    for (int mf = 0; mf < 5; mf++)
      Af[mf] = *(const i32x4*)(base + offB[mf]);

    i32x4 acc;
    acc[0] = 0; acc[1] = 0; acc[2] = 0; acc[3] = 0;
    #pragma unroll
    for (int mf = 0; mf < 5; mf++)
      acc = __builtin_amdgcn_mfma_i32_16x16x64_i8(Af[mf], bw[mf], acc, 0, 0, 0);

    // C 16x16: col=lane&15 (oc), row=(lane>>4)*4+reg (px). Sum valid pixels.
    int ssum = 0;
    #pragma unroll
    for (int j = 0; j < 4; j++) {
      int x = X0 + chunk * 4 + j;
      float yv = fmaf(scl, (float)acc[j], bias);
      int idx = (int)fminf(fmaxf(rintf(yv * inv8), 0.0f), 127.0f);
      if (x < 125) ssum += lut[idx];
    }
    ssum += __shfl_down(ssum, 32);
    ssum += __shfl_down(ssum, 16);
    if (lane < 16) atomicAdd(&gap_acc[n * 16 + oc], ssum);
  }
}

// ---------------------------------------------------------------------------
// pool_quant + classifier from GAP partials. 32 blocks x 64 thr.
// ---------------------------------------------------------------------------
__global__ __launch_bounds__(64) void k_fc(
    const int* __restrict__ gap_acc, const int* __restrict__ qwc,
    const float* __restrict__ bc, const float* __restrict__ scales,
    const float* __restrict__ wscale, float* __restrict__ out)
{
  __shared__ int sq[16];
  int n = blockIdx.x, tid = threadIdx.x;
  if (tid < 16) {
    int s = gap_acc[n * 16 + tid];
    float v = scales[9] * (float)s / 15625.0f;
    float r = fminf(fmaxf(rintf(v / scales[10]), -128.0f), 127.0f);
    sq[tid] = (int)r;
  }
  __syncthreads();
  if (tid < 10) {
    int acc = 0;
    #pragma unroll
    for (int k4 = 0; k4 < 4; k4++) {
      int wv = qwc[tid * 4 + k4];
      #pragma unroll
      for (int j = 0; j < 4; j++)
        acc += sq[k4 * 4 + j] * (int)(signed char)(wv >> (8 * j));
    }
    out[n * 10 + tid] = fmaf(scales[10] * wscale[4], (float)acc, bc[tid]);
  }
}

// ---------------------------------------------------------------------------
// Workspace layout (bytes), peak 101,259,264 (proven):
//   0         wscale (5 floats)
//   64        qw1   144 ints
//   1024      qw2B  1536 ints
//   8192      qw3B  6400 ints
//   36864     qw4B  1280 ints
//   43008     qwc   40 ints
//   49152     gap_acc 512 ints (2 KB) ... memset with wsraw
//   51200     wsraw 5 uints (atomicMax scratch)
//   65536     a2p [32][258][258][32] i8 = 68,161,536 -> ends 68,227,072
//   68227072  a1 [32][254][254][16] i8 = 33,032,192 -> ends 101,259,264
//             aliased by a3p (16,516,096; a1 dead by conv3)
// ---------------------------------------------------------------------------
extern "C" void kernel_launch(void* const* d_in, const int* in_sizes, int n_in,
                              void* d_out, int out_size, void* d_ws, size_t ws_size,
                              hipStream_t stream) {
  const float* x  = (const float*)d_in[0];
  const float* w1 = (const float*)d_in[1];
  const float* b1 = (const float*)d_in[2];
  const float* w2 = (const float*)d_in[3];
  const float* b2 = (const float*)d_in[4];
  const float* w3 = (const float*)d_in[5];
  const float* b3 = (const float*)d_in[6];
  const float* w4 = (const float*)d_in[7];
  const float* b4 = (const float*)d_in[8];
  const float* wc = (const float*)d_in[9];
  const float* bc = (const float*)d_in[10];
  const float* sc = (const float*)d_in[11];

  char* ws = (char*)d_ws;
  float* wscale = (float*)(ws + 0);
  int* qw1  = (int*)(ws + 64);
  int* qw2B = (int*)(ws + 1024);
  int* qw3B = (int*)(ws + 8192);
  int* qw4B = (int*)(ws + 36864);
  int* qwc  = (int*)(ws + 43008);
  int* gap_acc = (int*)(ws + 49152);
  unsigned int* wsraw = (unsigned int*)(ws + 51200);
  signed char* a2p = (signed char*)(ws + 65536);
  int*  a1  = (int*)(ws + 68227072);
  signed char* a3p = (signed char*)(ws + 68227072);  // alias (a1 dead by conv3)
  float* out = (float*)d_out;

  hipMemsetAsync(ws + 49152, 0, 4096, stream);       // gap_acc + wsraw
  k_wmax<<<40, 256, 0, stream>>>(w1, w2, w3, w4, wc, wsraw);
  k_wpack<<<40, 256, 0, stream>>>(w1, w2, w3, w4, wc, wsraw, wscale,
                                  qw1, qw2B, qw3B, qw4B, qwc);
  k_conv1<<<8065, 256, 0, stream>>>(x, qw1, b1, sc, wscale, a1);
  k_zero_border<<<256, 256, 0, stream>>>((int*)a2p);
  k_conv2_lds<<<4096, 256, 0, stream>>>(a1, qw2B, b2, sc, wscale, a2p);
  k_conv3pool_mfma<<<2048, 256, 0, stream>>>(a2p, qw3B, b3, sc, wscale, a3p);
  k_conv4_gap<<<2048, 256, 0, stream>>>(a3p, qw4B, b4, sc, wscale, gap_acc);
  k_fc<<<32, 64, 0, stream>>>(gap_acc, qwc, bc, sc, wscale, out);
}